// Round 4
// baseline (903.289 us; speedup 1.0000x reference)
//
#include <hip/hip_runtime.h>
#include <hip/hip_bf16.h>
#include <math.h>

#define TB 16
#define TS 512
#define TD 768
#define TH 3072
#define TNH 12
#define TE 7
#define TT (TB*TS)  // 8192 tokens

typedef __bf16 bf16x8_t __attribute__((ext_vector_type(8)));
typedef __bf16 bf16x4_t __attribute__((ext_vector_type(4)));
typedef float f32x4_t __attribute__((ext_vector_type(4)));

#define NEGINF (-__builtin_huge_valf())

// ---- workspace layout (bytes) ----
// split2 everywhere: x = h + m (bf16 planes), residual ~2^-18|x|.
#define O_APL   0ULL
#define O_VT0   0ULL
#define O_VT1   12582912ULL
#define O_CTXH  37748736ULL
#define O_CTXM  50331648ULL
#define O_QKH   62914560ULL
#define O_QKM   88080384ULL
#define O_VCOL  113246208ULL
#define O_BT    138412032ULL
#define O_META  149028864ULL
#define O_MIDG  150077440ULL
#define O_X2    62914560ULL
#define O_XG    75497472ULL   // xg during gemm1; re-used as part[] during gemm2/gather
#define O_W1T   0ULL
#define O_W2T   33030144ULL
// meta sub-offsets
#define M_CNT   0
#define M_FILL  64
#define M_NRB   192
#define M_RB2E  256
#define M_TOKE  1024
#define M_TOKW  66560
#define M_RGW   201216
#define M_TSLOT 270336

#define NRB_MAX 135
#define ROWCAP  17280

// ---------------- async global->LDS 16B ----------------
__device__ __forceinline__ void async16(const void* g, void* l) {
  __builtin_amdgcn_global_load_lds(
      (const __attribute__((address_space(1))) void*)g,
      (__attribute__((address_space(3))) void*)l, 16, 0, 0);
}

// ---------------- 2-way exact bf16 split ----------------
__device__ __forceinline__ void split2(float x, __bf16& h, __bf16& m) {
  h = (__bf16)x;
  m = (__bf16)(x - (float)h);
}

// ---------------- block reduction helper ----------------
__device__ __forceinline__ float block_sum256(float v, float* red4) {
  #pragma unroll
  for (int o = 32; o > 0; o >>= 1) v += __shfl_down(v, o, 64);
  int lane = threadIdx.x & 63, wv = threadIdx.x >> 6;
  if (lane == 0) red4[wv] = v;
  __syncthreads();
  float r = red4[0] + red4[1] + red4[2] + red4[3];
  __syncthreads();
  return r;
}

__global__ void init_meta_k(int* cnt) {
  if (threadIdx.x < TE) cnt[threadIdx.x] = 0;
}

// ---------------- LN1 fused with split2: hidden -> Apl planes ----------------
__global__ __launch_bounds__(256) void ln1_split_k(const float* __restrict__ in,
                                                   const float* __restrict__ g,
                                                   const float* __restrict__ bb,
                                                   __bf16* __restrict__ P) {
  __shared__ float red4[4];
  const size_t SA = (size_t)TT * TD;
  int row = blockIdx.x, tid = threadIdx.x;
  const float* x = in + (size_t)row * TD;
  float v0 = x[tid], v1 = x[tid + 256], v2 = x[tid + 512];
  float sum = block_sum256(v0 + v1 + v2, red4);
  float mean = sum * (1.0f / 768.0f);
  float d0 = v0 - mean, d1 = v1 - mean, d2 = v2 - mean;
  float var = block_sum256(d0*d0 + d1*d1 + d2*d2, red4) * (1.0f / 768.0f);
  float rs = rsqrtf(var + 1e-12f);
  float xn[3] = { g[tid]       * (d0 * rs) + bb[tid],
                  g[tid + 256] * (d1 * rs) + bb[tid + 256],
                  g[tid + 512] * (d2 * rs) + bb[tid + 512] };
  #pragma unroll
  for (int i = 0; i < 3; ++i) {
    __bf16 h, m; split2(xn[i], h, m);
    size_t o = (size_t)row * TD + tid + 256 * i;
    P[o] = h; P[SA + o] = m;
  }
}

// ---------------- transpose + 2-way split weights ----------------
__global__ void tpose_split2_k(const float* __restrict__ W0, const float* __restrict__ W1,
                               const float* __restrict__ W2,
                               __bf16* __restrict__ BT, size_t SB, int roffmul) {
  __shared__ float tile[32][33];
  const float* W = (blockIdx.z == 0) ? W0 : (blockIdx.z == 1) ? W1 : W2;
  int roff = roffmul * (int)blockIdx.z * TD;
  int c0 = blockIdx.x * 32, r0 = blockIdx.y * 32;
  int tx = threadIdx.x, ty = threadIdx.y;
  #pragma unroll
  for (int i = 0; i < 32; i += 8)
    tile[ty + i][tx] = W[(size_t)(r0 + ty + i) * TD + c0 + tx];
  __syncthreads();
  #pragma unroll
  for (int i = 0; i < 32; i += 8) {
    float x = tile[tx][ty + i];
    __bf16 h, m; split2(x, h, m);
    size_t o = (size_t)(roff + c0 + ty + i) * TD + r0 + tx;
    BT[o] = h; BT[SB + o] = m;
  }
}

// ---------------- split-bf16 4-pass GEMM: (Ah+Am)(Bh+Bm), full cross ----------------
// LDS: row-major [128][32] bf16/plane, 16B granule XOR-swizzled within row-pairs
// (pre-swizzled global source, since global_load_lds dest is linear); reads use
// qs = (q ^ ((lm>>1)&3))*8. 8-way conflict -> free 2-way.
template<int EPI>
__global__ __launch_bounds__(256) void gemm_split4_k(
    const __bf16* __restrict__ A0, const __bf16* __restrict__ A1,
    const __bf16* __restrict__ Bpl, size_t SB,
    const float* __restrict__ bi0, const float* __restrict__ bi1, const float* __restrict__ bi2,
    const float* __restrict__ resid, float* __restrict__ C,
    __bf16* __restrict__ qh_out, __bf16* __restrict__ qm_out, float* __restrict__ vout)
{
  __shared__ __align__(16) __bf16 As[2][4096];
  __shared__ __align__(16) __bf16 Bs[2][4096];
  const __bf16* Ap[2] = {A0, A1};
  int n0 = blockIdx.x * 128, m0 = blockIdx.y * 128;
  int tid = threadIdx.x;
  int wave = tid >> 6, lane = tid & 63;
  int wr = wave >> 1, wc = wave & 1;
  int lm = lane & 15, q = lane >> 4;
  int qs = (q ^ ((lm >> 1) & 3)) * 8;   // swizzled 16B-granule read offset
  f32x4_t acc[4][4];
  #pragma unroll
  for (int i = 0; i < 4; ++i)
    #pragma unroll
    for (int j = 0; j < 4; ++j) { f32x4_t z = {0.f,0.f,0.f,0.f}; acc[i][j] = z; }
  for (int k0 = 0; k0 < TD; k0 += 32) {
    #pragma unroll
    for (int it = 0; it < 2; ++it) {
      int f = it * 256 + tid; int r = f >> 2;
      int c8 = ((f & 3) ^ ((f >> 3) & 3)) * 8;   // pre-swizzled global chunk
      #pragma unroll
      for (int p = 0; p < 2; ++p) {
        async16(Ap[p] + (size_t)(m0 + r) * TD + k0 + c8, &As[p][f * 8]);
        async16(Bpl + p * SB + (size_t)(n0 + r) * TD + k0 + c8, &Bs[p][f * 8]);
      }
    }
    __syncthreads();
    bf16x8_t af[2][4];
    #pragma unroll
    for (int pa = 0; pa < 2; ++pa)
      #pragma unroll
      for (int i = 0; i < 4; ++i)
        af[pa][i] = *(const bf16x8_t*)(&As[pa][(wr*64 + i*16 + lm) * 32 + qs]);
    #pragma unroll
    for (int pb = 0; pb < 2; ++pb) {
      bf16x8_t bfr[4];
      #pragma unroll
      for (int j = 0; j < 4; ++j)
        bfr[j] = *(const bf16x8_t*)(&Bs[pb][(wc*64 + j*16 + lm) * 32 + qs]);
      #pragma unroll
      for (int pa = 0; pa < 2; ++pa)
        #pragma unroll
        for (int i = 0; i < 4; ++i)
          #pragma unroll
          for (int j = 0; j < 4; ++j)
            acc[i][j] = __builtin_amdgcn_mfma_f32_16x16x32_bf16(af[pa][i], bfr[j], acc[i][j], 0, 0, 0);
    }
    __syncthreads();
  }
  #pragma unroll
  for (int i = 0; i < 4; ++i) {
    #pragma unroll
    for (int j = 0; j < 4; ++j) {
      #pragma unroll
      for (int r = 0; r < 4; ++r) {
        int row = m0 + wr*64 + i*16 + q*4 + r;
        int col = n0 + wc*64 + j*16 + lm;
        float v = acc[i][j][r];
        if (EPI == 0) {
          float bias = (col < 768) ? bi0[col] : (col < 1536) ? bi1[col - 768] : bi2[col - 1536];
          v += bias;
          if (col < 768) v *= 0.125f;
          if (col < 1536) {
            __bf16 hh = (__bf16)v; float r1 = v - (float)hh;
            qh_out[(size_t)row * 1536 + col] = hh;
            qm_out[(size_t)row * 1536 + col] = (__bf16)r1;
          } else {
            vout[(size_t)row * TD + (col - 1536)] = v;
          }
        } else {
          v += bi0[col] + resid[(size_t)row * TD + col];
          C[(size_t)row * TD + col] = v;
        }
      }
    }
  }
}

// ---------------- V transpose + split2 ----------------
__global__ void vT_split2_k(const float* __restrict__ vcol,
                            __bf16* __restrict__ v0, __bf16* __restrict__ v1) {
  __shared__ float tile[32][33];
  int s0 = blockIdx.x * 32, d0 = blockIdx.y * 32, bh = blockIdx.z;
  int b = bh / 12, h = bh - b * 12;
  int tx = threadIdx.x, ty = threadIdx.y;
  #pragma unroll
  for (int i = 0; i < 32; i += 8)
    tile[ty + i][tx] = vcol[(size_t)(b * TS + s0 + ty + i) * TD + h * 64 + d0 + tx];
  __syncthreads();
  #pragma unroll
  for (int i = 0; i < 32; i += 8) {
    float x = tile[tx][ty + i];
    __bf16 hh, mm; split2(x, hh, mm);
    size_t o = (size_t)(bh * 64 + d0 + ty + i) * TS + s0 + tx;
    v0[o] = hh; v1[o] = mm;
  }
}

// ---------------- MFMA flash attention (2-plane P/V, 4-pass PV) ----------------
#define AST 72
__global__ __launch_bounds__(256) void attn_mfma_k(
    const __bf16* __restrict__ qkh, const __bf16* __restrict__ qkm,
    const __bf16* __restrict__ vT0, const __bf16* __restrict__ vT1,
    const int* __restrict__ mask,
    __bf16* __restrict__ ch, __bf16* __restrict__ cm)
{
  __shared__ __align__(16) __bf16 KS[2][64 * AST];
  __shared__ __align__(16) __bf16 VS[2][64 * AST];
  __shared__ __align__(16) __bf16 PS[2][64 * AST];
  __shared__ float maskadd[512];
  int qt = blockIdx.x, h = blockIdx.y, b = blockIdx.z;
  int tid = threadIdx.x, w = tid >> 6, lane = tid & 63;
  int lm = lane & 15, quad = lane >> 4;
  int t0 = b * TS, t0q = t0 + qt * 64, bh = b * TNH + h;
  for (int i = tid; i < 512; i += 256)
    maskadd[i] = (mask[t0 + i] != 0) ? 0.0f : -1e30f;
  #pragma unroll
  for (int it = 0; it < 2; ++it) {
    int f = it * 256 + tid, r = f >> 3, c8 = (f & 7) * 8;
    *(uint4*)&PS[0][r * AST + c8] = *(const uint4*)(qkh + (size_t)(t0q + r) * 1536 + h * 64 + c8);
    *(uint4*)&PS[1][r * AST + c8] = *(const uint4*)(qkm + (size_t)(t0q + r) * 1536 + h * 64 + c8);
  }
  __syncthreads();
  bf16x8_t qf[2][2];
  #pragma unroll
  for (int p = 0; p < 2; ++p)
    #pragma unroll
    for (int ks = 0; ks < 2; ++ks)
      qf[p][ks] = *(const bf16x8_t*)&PS[p][(w * 16 + lm) * AST + ks * 32 + quad * 8];
  __syncthreads();
  f32x4_t Oacc[4];
  #pragma unroll
  for (int j = 0; j < 4; ++j) { f32x4_t z = {0.f,0.f,0.f,0.f}; Oacc[j] = z; }
  float mst[4], lst[4];
  #pragma unroll
  for (int r = 0; r < 4; ++r) { mst[r] = -3.0e38f; lst[r] = 0.0f; }

  for (int kc = 0; kc < 8; ++kc) {
    #pragma unroll
    for (int it = 0; it < 2; ++it) {
      int f = it * 256 + tid, r = f >> 3, c8 = (f & 7) * 8;
      size_t ksrc = (size_t)(t0 + kc * 64 + r) * 1536 + 768 + h * 64 + c8;
      *(uint4*)&KS[0][r * AST + c8] = *(const uint4*)(qkh + ksrc);
      *(uint4*)&KS[1][r * AST + c8] = *(const uint4*)(qkm + ksrc);
      size_t vsrc = (size_t)(bh * 64 + r) * TS + kc * 64 + c8;
      *(uint4*)&VS[0][r * AST + c8] = *(const uint4*)(vT0 + vsrc);
      *(uint4*)&VS[1][r * AST + c8] = *(const uint4*)(vT1 + vsrc);
    }
    __syncthreads();
    f32x4_t sacc[4];
    #pragma unroll
    for (int j = 0; j < 4; ++j) { f32x4_t z = {0.f,0.f,0.f,0.f}; sacc[j] = z; }
    #pragma unroll
    for (int ks = 0; ks < 2; ++ks) {
      bf16x8_t kh_[4], km_[4];
      #pragma unroll
      for (int jn = 0; jn < 4; ++jn) {
        kh_[jn] = *(const bf16x8_t*)&KS[0][(jn*16 + lm) * AST + ks*32 + quad*8];
        km_[jn] = *(const bf16x8_t*)&KS[1][(jn*16 + lm) * AST + ks*32 + quad*8];
      }
      #pragma unroll
      for (int jn = 0; jn < 4; ++jn)
        sacc[jn] = __builtin_amdgcn_mfma_f32_16x16x32_bf16(qf[0][ks], kh_[jn], sacc[jn], 0,0,0);
      #pragma unroll
      for (int jn = 0; jn < 4; ++jn)
        sacc[jn] = __builtin_amdgcn_mfma_f32_16x16x32_bf16(qf[0][ks], km_[jn], sacc[jn], 0,0,0);
      #pragma unroll
      for (int jn = 0; jn < 4; ++jn)
        sacc[jn] = __builtin_amdgcn_mfma_f32_16x16x32_bf16(qf[1][ks], kh_[jn], sacc[jn], 0,0,0);
    }
    float s[4][4];
    #pragma unroll
    for (int jn = 0; jn < 4; ++jn)
      #pragma unroll
      for (int r = 0; r < 4; ++r)
        s[jn][r] = sacc[jn][r] + maskadd[kc*64 + jn*16 + lm];
    float alpha[4];
    #pragma unroll
    for (int r = 0; r < 4; ++r) {
      float rmax = fmaxf(fmaxf(s[0][r], s[1][r]), fmaxf(s[2][r], s[3][r]));
      #pragma unroll
      for (int mk = 1; mk < 16; mk <<= 1)
        rmax = fmaxf(rmax, __shfl_xor(rmax, mk, 64));
      float mnew = fmaxf(mst[r], rmax);
      alpha[r] = expf(mst[r] - mnew);
      mst[r] = mnew;
      float psum = 0.0f;
      #pragma unroll
      for (int jn = 0; jn < 4; ++jn) {
        float p = expf(s[jn][r] - mnew);
        s[jn][r] = p;
        psum += p;
      }
      #pragma unroll
      for (int mk = 1; mk < 16; mk <<= 1)
        psum += __shfl_xor(psum, mk, 64);
      lst[r] = lst[r] * alpha[r] + psum;
    }
    #pragma unroll
    for (int jn = 0; jn < 4; ++jn)
      #pragma unroll
      for (int r = 0; r < 4; ++r)
        Oacc[jn][r] *= alpha[r];
    #pragma unroll
    for (int jn = 0; jn < 4; ++jn)
      #pragma unroll
      for (int r = 0; r < 4; ++r) {
        __bf16 ph, pm; split2(s[jn][r], ph, pm);
        int pa = (w*16 + quad*4 + r) * AST + jn*16 + lm;
        PS[0][pa] = ph; PS[1][pa] = pm;
      }
    __syncthreads();
    #pragma unroll
    for (int ks = 0; ks < 2; ++ks) {
      bf16x8_t af[2];
      #pragma unroll
      for (int p = 0; p < 2; ++p)
        af[p] = *(const bf16x8_t*)&PS[p][(w*16 + lm) * AST + ks*32 + quad*8];
      bf16x8_t vf[2][4];
      #pragma unroll
      for (int p = 0; p < 2; ++p)
        #pragma unroll
        for (int jn = 0; jn < 4; ++jn)
          vf[p][jn] = *(const bf16x8_t*)&VS[p][(jn*16 + lm) * AST + ks*32 + quad*8];
      #pragma unroll
      for (int jn = 0; jn < 4; ++jn) {
        Oacc[jn] = __builtin_amdgcn_mfma_f32_16x16x32_bf16(af[0], vf[0][jn], Oacc[jn], 0,0,0);
        Oacc[jn] = __builtin_amdgcn_mfma_f32_16x16x32_bf16(af[0], vf[1][jn], Oacc[jn], 0,0,0);
        Oacc[jn] = __builtin_amdgcn_mfma_f32_16x16x32_bf16(af[1], vf[0][jn], Oacc[jn], 0,0,0);
        Oacc[jn] = __builtin_amdgcn_mfma_f32_16x16x32_bf16(af[1], vf[1][jn], Oacc[jn], 0,0,0);
      }
    }
    __syncthreads();
  }
  float linv[4];
  #pragma unroll
  for (int r = 0; r < 4; ++r) linv[r] = 1.0f / lst[r];
  #pragma unroll
  for (int jn = 0; jn < 4; ++jn)
    #pragma unroll
    for (int r = 0; r < 4; ++r) {
      float o = Oacc[jn][r] * linv[r];
      __bf16 hh, mm; split2(o, hh, mm);
      size_t oo = (size_t)(t0q + w*16 + quad*4 + r) * TD + h*64 + jn*16 + lm;
      ch[oo] = hh; cm[oo] = mm;
    }
}

// ---------------- LN2 + gate (no atomics; routing handled by hist/slot kernels) ----
__global__ __launch_bounds__(256) void ln2_gate_k(const float* __restrict__ attn,
                                                  const float* __restrict__ g,
                                                  const float* __restrict__ bb,
                                                  const float* __restrict__ gw,
                                                  const float* __restrict__ gb,
                                                  __bf16* __restrict__ x2,
                                                  float* __restrict__ gates,
                                                  int* __restrict__ tok_e,
                                                  float* __restrict__ tok_w) {
  __shared__ float red4[4];
  __shared__ float redc[4][7];
  int row = blockIdx.x, tid = threadIdx.x;
  const float* x = attn + (size_t)row * TD;
  float v0 = x[tid], v1 = x[tid + 256], v2 = x[tid + 512];
  float sum = block_sum256(v0 + v1 + v2, red4);
  float mean = sum * (1.0f / 768.0f);
  float d0 = v0 - mean, d1 = v1 - mean, d2 = v2 - mean;
  float var = block_sum256(d0*d0 + d1*d1 + d2*d2, red4) * (1.0f / 768.0f);
  float rs = rsqrtf(var + 1e-12f);
  float xn0 = g[tid]       * (d0 * rs) + bb[tid];
  float xn1 = g[tid + 256] * (d1 * rs) + bb[tid + 256];
  float xn2 = g[tid + 512] * (d2 * rs) + bb[tid + 512];
  __bf16* xo = x2 + (size_t)row * TD;
  xo[tid] = (__bf16)xn0; xo[tid + 256] = (__bf16)xn1; xo[tid + 512] = (__bf16)xn2;
  float p[7];
  const float* w0 = gw + (size_t)tid * 7;
  const float* w1p = gw + (size_t)(tid + 256) * 7;
  const float* w2p = gw + (size_t)(tid + 512) * 7;
  #pragma unroll
  for (int e = 0; e < 7; ++e) p[e] = xn0 * w0[e] + xn1 * w1p[e] + xn2 * w2p[e];
  #pragma unroll
  for (int e = 0; e < 7; ++e)
    #pragma unroll
    for (int o = 32; o > 0; o >>= 1) p[e] += __shfl_down(p[e], o, 64);
  int lane = tid & 63, wv = tid >> 6;
  if (lane == 0) {
    #pragma unroll
    for (int e = 0; e < 7; ++e) redc[wv][e] = p[e];
  }
  __syncthreads();
  if (tid == 0) {
    float l[7];
    #pragma unroll
    for (int e = 0; e < 7; ++e)
      l[e] = redc[0][e] + redc[1][e] + redc[2][e] + redc[3][e] + gb[e];
    int i1 = 0;
    for (int e = 1; e < 7; ++e) if (l[e] > l[i1]) i1 = e;
    int i2 = -1;
    for (int e = 0; e < 7; ++e) if (e != i1 && (i2 < 0 || l[e] > l[i2])) i2 = e;
    float m = l[i1];
    float e1 = expf(l[i1] - m), e2 = expf(l[i2] - m);
    float inv = 1.0f / (e1 + e2);
    float g1 = e1 * inv, g2 = e2 * inv;
    float* go = gates + (size_t)row * 7;
    #pragma unroll
    for (int e = 0; e < 7; ++e) go[e] = 0.0f;
    go[i1] = g1; go[i2] = g2;
    tok_e[row * 2] = i1; tok_e[row * 2 + 1] = i2;
    tok_w[row * 2] = g1; tok_w[row * 2 + 1] = g2;
  }
}

// ---------------- histogram of expert assignments (ballot-aggregated) ----------------
__global__ __launch_bounds__(256) void hist_k(const int* __restrict__ tok_e,
                                              int* __restrict__ cnt) {
  __shared__ int hloc[TE];
  int i = blockIdx.x * 256 + threadIdx.x;
  int e = tok_e[i];
  if (threadIdx.x < TE) hloc[threadIdx.x] = 0;
  __syncthreads();
  #pragma unroll
  for (int ee = 0; ee < TE; ++ee) {
    unsigned long long m = __ballot(e == ee);
    if ((threadIdx.x & 63) == 0 && m) atomicAdd(&hloc[ee], (int)__popcll(m));
  }
  __syncthreads();
  if (threadIdx.x < TE) atomicAdd(&cnt[threadIdx.x], hloc[threadIdx.x]);
}

// ---------------- prefix (parallel rb2e fill) ----------------
__global__ void prefix_k(const int* __restrict__ cnt, int* __restrict__ fill,
                         int* __restrict__ nrb_p, int* __restrict__ rb2e) {
  __shared__ int start[TE + 1];
  if (threadIdx.x == 0) {
    int acc = 0;
    for (int e = 0; e < TE; ++e) {
      start[e] = acc;
      int nb = (cnt[e] + 127) >> 7;
      fill[e] = acc * 128;
      acc += nb;
    }
    start[TE] = acc;
    nrb_p[0] = acc;
  }
  __syncthreads();
  for (int b = threadIdx.x; b < start[TE]; b += blockDim.x) {
    int e = 0;
    while (start[e + 1] <= b) ++e;
    rb2e[b] = e;
  }
}

// ---------------- slot assignment: ballot rank + per-block aggregated atomic ----------------
__global__ __launch_bounds__(256) void slot_assign_k(const int* __restrict__ tok_e,
                                                     const float* __restrict__ tok_w,
                                                     int* __restrict__ fill,
                                                     int* __restrict__ tok_slot,
                                                     float* __restrict__ row_gw) {
  __shared__ int wcnt[4][TE];
  __shared__ int wbase[4][TE];
  int i = blockIdx.x * 256 + threadIdx.x;
  int e = tok_e[i];
  int lane = threadIdx.x & 63, wv = threadIdx.x >> 6;
  unsigned long long lt = (1ULL << lane) - 1ULL;
  int myrank = 0;
  #pragma unroll
  for (int ee = 0; ee < TE; ++ee) {
    unsigned long long m = __ballot(e == ee);
    if (e == ee) myrank = (int)__popcll(m & lt);
    if (lane == 0) wcnt[wv][ee] = (int)__popcll(m);
  }
  __syncthreads();
  if (threadIdx.x < TE) {
    int ee = threadIdx.x;
    int c0 = wcnt[0][ee], c1 = wcnt[1][ee], c2 = wcnt[2][ee], c3 = wcnt[3][ee];
    int base = atomicAdd(&fill[ee], c0 + c1 + c2 + c3);
    wbase[0][ee] = base;
    wbase[1][ee] = base + c0;
    wbase[2][ee] = base + c0 + c1;
    wbase[3][ee] = base + c0 + c1 + c2;
  }
  __syncthreads();
  int slot = wbase[wv][e] + myrank;
  tok_slot[i] = slot;
  row_gw[slot] = tok_w[i];
}

// ---------------- copy token rows to grouped buffer (no atomics) ----------------
__global__ __launch_bounds__(192) void copy_xg_k(const __bf16* __restrict__ x2,
                                                 const int* __restrict__ tok_slot,
                                                 __bf16* __restrict__ xg) {
  int t = blockIdx.x, tid = threadIdx.x;
  int j = tid / 96, c = tid - j * 96;
  int s = tok_slot[t * 2 + j];
  *(uint4*)(xg + (size_t)s * TD + c * 8) =
      *(const uint4*)(x2 + (size_t)t * TD + c * 8);
}

// ---------------- transpose + cast fp32 -> bf16 ----------------
__global__ void transpose_cast_k(const float* __restrict__ in, __bf16* __restrict__ out,
                                 int R, int C) {
  __shared__ float tile[32][33];
  size_t zoff = (size_t)blockIdx.z * R * C;
  const float* ip = in + zoff;
  __bf16* op = out + zoff;
  int c0 = blockIdx.x * 32, r0 = blockIdx.y * 32;
  int tx = threadIdx.x, ty = threadIdx.y;
  #pragma unroll
  for (int i = 0; i < 32; i += 8)
    tile[ty + i][tx] = ip[(size_t)(r0 + ty + i) * C + c0 + tx];
  __syncthreads();
  #pragma unroll
  for (int i = 0; i < 32; i += 8)
    op[(size_t)(c0 + ty + i) * R + r0 + tx] = (__bf16)tile[tx][ty + i];
}

// ---------------- sparse FFN GEMM1 (2-deep prefetch pipeline) ----------------
// T3-minimum: issue STAGE(next) before ds_read+MFMA(cur); one barrier per K-step.
// Loads for tile k+1 land during compute of tile k instead of stalling serially.
__global__ __launch_bounds__(256) void gemm1_k(
    const __bf16* __restrict__ xg, const __bf16* __restrict__ w1T,
    const float* __restrict__ b1, const int* __restrict__ rb2e,
    const int* __restrict__ nrb_p, int cb, __bf16* __restrict__ midg)
{
  int rb = cb + blockIdx.y;
  if (rb >= nrb_p[0]) return;
  int e = rb2e[rb];
  __shared__ __align__(16) __bf16 As[2][4096];
  __shared__ __align__(16) __bf16 Bs[2][4096];
  const __bf16* A = xg + (size_t)rb * 128 * TD;
  const __bf16* BT = w1T + (size_t)e * TH * TD;
  const float* be = b1 + (size_t)e * TH;
  int n0 = blockIdx.x * 128;
  int tid = threadIdx.x;
  int wave = tid >> 6, lane = tid & 63;
  int wr = wave >> 1, wc = wave & 1;
  int lm = lane & 15, q = lane >> 4;
  int qs = (q ^ ((lm >> 1) & 3)) * 8;
  f32x4_t acc[4][4];
  #pragma unroll
  for (int i = 0; i < 4; ++i)
    #pragma unroll
    for (int j = 0; j < 4; ++j) { f32x4_t z = {0.f,0.f,0.f,0.f}; acc[i][j] = z; }

  // stage one K-tile (k0) into buffer buf
  int r_ = tid >> 2;
  int c8_ = ((tid & 3) ^ ((tid >> 3) & 3)) * 8;
  int r2_ = (256 + tid) >> 2;
  int c82_ = (((256 + tid) & 3) ^ (((256 + tid) >> 3) & 3)) * 8;

  #define G1_STAGE(buf, k0) do { \
    async16(A + (size_t)r_ * TD + (k0) + c8_, &As[buf][tid * 8]); \
    async16(BT + (size_t)(n0 + r_) * TD + (k0) + c8_, &Bs[buf][tid * 8]); \
    async16(A + (size_t)r2_ * TD + (k0) + c82_, &As[buf][(256 + tid) * 8]); \
    async16(BT + (size_t)(n0 + r2_) * TD + (k0) + c82_, &Bs[buf][(256 + tid) * 8]); \
  } while (0)

  const int NT = TD / 32;  // 24
  G1_STAGE(0, 0);
  __syncthreads();
  int cur = 0;
  for (int t = 0; t < NT; ++t) {
    if (t + 1 < NT) G1_STAGE(cur ^ 1, (t + 1) * 32);
    bf16x8_t af[4], bfr[4];
    #pragma unroll
    for (int i = 0; i < 4; ++i) af[i]  = *(const bf16x8_t*)(&As[cur][(wr*64 + i*16 + lm)*32 + qs]);
    #pragma unroll
    for (int j = 0; j < 4; ++j) bfr[j] = *(const bf16x8_t*)(&Bs[cur][(wc*64 + j*16 + lm)*32 + qs]);
    #pragma unroll
    for (int i = 0; i < 4; ++i)
      #pragma unroll
      for (int j = 0; j < 4; ++j)
        acc[i][j] = __builtin_amdgcn_mfma_f32_16x16x32_bf16(af[i], bfr[j], acc[i][j], 0, 0, 0);
    __syncthreads();   // drains next-tile loads (overlapped with MFMA) + read-before-write fence
    cur ^= 1;
  }
  #undef G1_STAGE

  #pragma unroll
  for (int i = 0; i < 4; ++i) {
    #pragma unroll
    for (int j = 0; j < 4; ++j) {
      #pragma unroll
      for (int r = 0; r < 4; ++r) {
        int row = wr*64 + i*16 + q*4 + r;
        int col = n0 + wc*64 + j*16 + lm;
        float v = acc[i][j][r] + be[col];
        v = 0.5f * v * (1.0f + erff(v * 0.70710678118654752f));
        midg[(size_t)(blockIdx.y * 128 + row) * TH + col] = (__bf16)v;
      }
    }
  }
}

// ---------------- sparse FFN GEMM2 (2-deep prefetch pipeline) ----------------
__global__ __launch_bounds__(256) void gemm2_k(
    const __bf16* __restrict__ midg, const __bf16* __restrict__ w2T,
    const float* __restrict__ b2, const int* __restrict__ rb2e,
    const int* __restrict__ nrb_p, const float* __restrict__ row_gw,
    int cb, __bf16* __restrict__ part)
{
  int rb = cb + blockIdx.y;
  if (rb >= nrb_p[0]) return;
  int e = rb2e[rb];
  __shared__ __align__(16) __bf16 As[2][4096];
  __shared__ __align__(16) __bf16 Bs[2][4096];
  const __bf16* A = midg + (size_t)blockIdx.y * 128 * TH;
  const __bf16* BT = w2T + (size_t)e * TD * TH;
  const float* be = b2 + (size_t)e * TD;
  int n0 = blockIdx.x * 128;
  int tid = threadIdx.x;
  int wave = tid >> 6, lane = tid & 63;
  int wr = wave >> 1, wc = wave & 1;
  int lm = lane & 15, q = lane >> 4;
  int qs = (q ^ ((lm >> 1) & 3)) * 8;
  f32x4_t acc[4][4];
  #pragma unroll
  for (int i = 0; i < 4; ++i)
    #pragma unroll
    for (int j = 0; j < 4; ++j) { f32x4_t z = {0.f,0.f,0.f,0.f}; acc[i][j] = z; }

  int r_ = tid >> 2;
  int c8_ = ((tid & 3) ^ ((tid >> 3) & 3)) * 8;
  int r2_ = (256 + tid) >> 2;
  int c82_ = (((256 + tid) & 3) ^ (((256 + tid) >> 3) & 3)) * 8;

  #define G2_STAGE(buf, k0) do { \
    async16(A + (size_t)r_ * TH + (k0) + c8_, &As[buf][tid * 8]); \
    async16(BT + (size_t)(n0 + r_) * TH + (k0) + c8_, &Bs[buf][tid * 8]); \
    async16(A + (size_t)r2_ * TH + (k0) + c82_, &As[buf][(256 + tid) * 8]); \
    async16(BT + (size_t)(n0 + r2_) * TH + (k0) + c82_, &Bs[buf][(256 + tid) * 8]); \
  } while (0)

  const int NT = TH / 32;  // 96
  G2_STAGE(0, 0);
  __syncthreads();
  int cur = 0;
  for (int t = 0; t < NT; ++t) {
    if (t + 1 < NT) G2_STAGE(cur ^ 1, (t + 1) * 32);
    bf16x8_t af[4], bfr[4];
    #pragma unroll
    for (int i = 0; i < 4; ++i) af[i]  = *(const bf16x8_t*)(&As[cur][(wr*64 + i*16 + lm)*32 + qs]);
    #pragma unroll
    for (int j = 0; j < 4; ++j) bfr[j] = *(const bf16x8_t*)(&Bs[cur][(wc*64 + j*16 + lm)*32 + qs]);
    #pragma unroll
    for (int i = 0; i < 4; ++i)
      #pragma unroll
      for (int j = 0; j < 4; ++j)
        acc[i][j] = __builtin_amdgcn_mfma_f32_16x16x32_bf16(af[i], bfr[j], acc[i][j], 0, 0, 0);
    __syncthreads();
    cur ^= 1;
  }
  #undef G2_STAGE

  #pragma unroll
  for (int i = 0; i < 4; ++i) {
    #pragma unroll
    for (int r = 0; r < 4; ++r) {
      int row = wr*64 + i*16 + q*4 + r;
      int grow = rb * 128 + row;
      float gwt = row_gw[grow];
      #pragma unroll
      for (int j = 0; j < 4; ++j) {
        int col = n0 + wc*64 + j*16 + lm;
        part[(size_t)grow * TD + col] = (__bf16)(gwt * (acc[i][j][r] + be[col]));
      }
    }
  }
}

// ---------------- gather: out[t] += part[slot0] + part[slot1] ----------------
__global__ __launch_bounds__(192) void gather_k(const __bf16* __restrict__ part,
                                                const int* __restrict__ tok_slot,
                                                float* __restrict__ outp) {
  int t = blockIdx.x, tid = threadIdx.x;
  int s0 = tok_slot[t * 2], s1 = tok_slot[t * 2 + 1];
  int c = tid * 4;
  float4 o = *(float4*)(outp + (size_t)t * TD + c);
  bf16x4_t p0 = *(const bf16x4_t*)(part + (size_t)s0 * TD + c);
  bf16x4_t p1 = *(const bf16x4_t*)(part + (size_t)s1 * TD + c);
  o.x += (float)p0[0] + (float)p1[0];
  o.y += (float)p0[1] + (float)p1[1];
  o.z += (float)p0[2] + (float)p1[2];
  o.w += (float)p0[3] + (float)p1[3];
  *(float4*)(outp + (size_t)t * TD + c) = o;
}

// ---------------- host launcher ----------------
extern "C" void kernel_launch(void* const* d_in, const int* in_sizes, int n_in,
                              void* d_out, int out_size, void* d_ws, size_t ws_size,
                              hipStream_t stream) {
  (void)in_sizes; (void)n_in; (void)out_size;
  const float* hidden = (const float*)d_in[0];
  const int*   mask   = (const int*)d_in[1];
  const float* ln1_g  = (const float*)d_in[2];
  const float* ln1_b  = (const float*)d_in[3];
  const float* wq = (const float*)d_in[4];  const float* bq = (const float*)d_in[5];
  const float* wk = (const float*)d_in[6];  const float* bk = (const float*)d_in[7];
  const float* wv = (const float*)d_in[8];  const float* bv = (const float*)d_in[9];
  const float* wo = (const float*)d_in[10]; const float* bo = (const float*)d_in[11];
  const float* gate_w = (const float*)d_in[12];
  const float* gate_b = (const float*)d_in[13];
  const float* w1 = (const float*)d_in[14];
  const float* b1 = (const float*)d_in[15];
  const float* w2 = (const float*)d_in[16];
  const float* b2 = (const float*)d_in[17];
  const float* ln2_g = (const float*)d_in[18];
  const float* ln2_b = (const float*)d_in[19];

  float* outp  = (float*)d_out;
  float* gates = (float*)d_out + (size_t)TT * TD;

  char* ws = (char*)d_ws;
  __bf16* Apl  = (__bf16*)(ws + O_APL);
  __bf16* vT0p = (__bf16*)(ws + O_VT0);
  __bf16* vT1p = (__bf16*)(ws + O_VT1);
  __bf16* ctxh = (__bf16*)(ws + O_CTXH);
  __bf16* ctxm = (__bf16*)(ws + O_CTXM);
  __bf16* qkh  = (__bf16*)(ws + O_QKH);
  __bf16* qkm  = (__bf16*)(ws + O_QKM);
  float*  vcol = (float*)(ws + O_VCOL);
  __bf16* BTp  = (__bf16*)(ws + O_BT);
  __bf16* x2   = (__bf16*)(ws + O_X2);
  __bf16* xg   = (__bf16*)(ws + O_XG);   // also part[] (gemm2 output, after gemm1 consumed xg)
  __bf16* w1T  = (__bf16*)(ws + O_W1T);
  __bf16* w2T  = (__bf16*)(ws + O_W2T);
  char*   meta = ws + O_META;
  int*   cnt      = (int*)(meta + M_CNT);
  int*   fill     = (int*)(meta + M_FILL);
  int*   nrb_p    = (int*)(meta + M_NRB);
  int*   rb2e     = (int*)(meta + M_RB2E);
  int*   tok_e    = (int*)(meta + M_TOKE);
  float* tok_w    = (float*)(meta + M_TOKW);
  float* row_gw   = (float*)(meta + M_RGW);
  int*   tok_slot = (int*)(meta + M_TSLOT);
  __bf16* midg = (__bf16*)(ws + O_MIDG);

  long long midcap = (long long)ws_size - (long long)O_MIDG;
  int crb = (int)(midcap / (128LL * TH * 2));
  if (crb < 1) crb = 1;
  if (crb > NRB_MAX) crb = NRB_MAX;

  const size_t SA = (size_t)TT * TD;

  init_meta_k<<<1, 64, 0, stream>>>(cnt);
  ln1_split_k<<<TT, 256, 0, stream>>>(hidden, ln1_g, ln1_b, Apl);
  tpose_split2_k<<<dim3(24, 24, 3), dim3(32, 8), 0, stream>>>(
      wq, wk, wv, BTp, (size_t)2304 * TD, 1);
  gemm_split4_k<0><<<dim3(18, 64), 256, 0, stream>>>(
      Apl, Apl + SA, BTp, (size_t)2304 * TD,
      bq, bk, bv, nullptr, nullptr, qkh, qkm, vcol);
  vT_split2_k<<<dim3(16, 2, 192), dim3(32, 8), 0, stream>>>(vcol, vT0p, vT1p);
  attn_mfma_k<<<dim3(8, TNH, TB), 256, 0, stream>>>(
      qkh, qkm, vT0p, vT1p, mask, ctxh, ctxm);
  tpose_split2_k<<<dim3(24, 24, 1), dim3(32, 8), 0, stream>>>(
      wo, wo, wo, BTp, (size_t)TD * TD, 0);
  gemm_split4_k<1><<<dim3(6, 64), 256, 0, stream>>>(
      ctxh, ctxm, BTp, (size_t)TD * TD,
      bo, nullptr, nullptr, hidden, outp, nullptr, nullptr, nullptr);
  ln2_gate_k<<<TT, 256, 0, stream>>>(outp, ln2_g, ln2_b, gate_w, gate_b, x2, gates,
                                     tok_e, tok_w);
  hist_k<<<64, 256, 0, stream>>>(tok_e, cnt);
  prefix_k<<<1, 192, 0, stream>>>(cnt, fill, nrb_p, rb2e);
  slot_assign_k<<<64, 256, 0, stream>>>(tok_e, tok_w, fill, tok_slot, row_gw);
  copy_xg_k<<<TT, 192, 0, stream>>>(x2, tok_slot, xg);
  transpose_cast_k<<<dim3(TH / 32, TD / 32, TE), dim3(32, 8), 0, stream>>>(w1, w1T, TD, TH);
  transpose_cast_k<<<dim3(TD / 32, TH / 32, TE), dim3(32, 8), 0, stream>>>(w2, w2T, TH, TD);
  __bf16* part = xg;  // xg rows of chunk c are dead once gemm1(c) has read them
  for (int cb = 0; cb < NRB_MAX; cb += crb) {
    int nb = NRB_MAX - cb; if (nb > crb) nb = crb;
    gemm1_k<<<dim3(TH / 128, nb), 256, 0, stream>>>(xg, w1T, b1, rb2e, nrb_p, cb, midg);
    gemm2_k<<<dim3(TD / 128, nb), 256, 0, stream>>>(midg, w2T, b2, rb2e, nrb_p,
                                                    row_gw, cb, part);
  }
  gather_k<<<TT, 192, 0, stream>>>(part, tok_slot, outp);
}

// Round 5
// 886.747 us; speedup vs baseline: 1.0187x; 1.0187x over previous
//
#include <hip/hip_runtime.h>
#include <hip/hip_bf16.h>
#include <math.h>

#define TB 16
#define TS 512
#define TD 768
#define TH 3072
#define TNH 12
#define TE 7
#define TT (TB*TS)  // 8192 tokens

typedef __bf16 bf16x8_t __attribute__((ext_vector_type(8)));
typedef __bf16 bf16x4_t __attribute__((ext_vector_type(4)));
typedef float f32x4_t __attribute__((ext_vector_type(4)));

#define NEGINF (-__builtin_huge_valf())

// ---- workspace layout (bytes) ----
// split2 everywhere: x = h + m (bf16 planes), residual ~2^-18|x|.
#define O_APL   0ULL
#define O_VT0   0ULL
#define O_VT1   12582912ULL
#define O_CTXH  37748736ULL
#define O_CTXM  50331648ULL
#define O_QKH   62914560ULL
#define O_QKM   88080384ULL
#define O_VCOL  113246208ULL
#define O_BT    138412032ULL
#define O_META  149028864ULL
#define O_MIDG  150077440ULL
#define O_X2    62914560ULL
#define O_XG    75497472ULL   // xg during gemm1; re-used as part[] during gemm2/gather
#define O_W1T   0ULL
#define O_W2T   33030144ULL
// meta sub-offsets
#define M_CNT   0
#define M_FILL  64
#define M_NRB   192
#define M_RB2E  256
#define M_TOKE  1024
#define M_TOKW  66560
#define M_RGW   201216
#define M_TSLOT 270336

#define NRB_MAX 135
#define ROWCAP  17280

// ---------------- async global->LDS 16B ----------------
__device__ __forceinline__ void async16(const void* g, void* l) {
  __builtin_amdgcn_global_load_lds(
      (const __attribute__((address_space(1))) void*)g,
      (__attribute__((address_space(3))) void*)l, 16, 0, 0);
}

// ---------------- 2-way exact bf16 split ----------------
__device__ __forceinline__ void split2(float x, __bf16& h, __bf16& m) {
  h = (__bf16)x;
  m = (__bf16)(x - (float)h);
}

// ---------------- block reduction helper ----------------
__device__ __forceinline__ float block_sum256(float v, float* red4) {
  #pragma unroll
  for (int o = 32; o > 0; o >>= 1) v += __shfl_down(v, o, 64);
  int lane = threadIdx.x & 63, wv = threadIdx.x >> 6;
  if (lane == 0) red4[wv] = v;
  __syncthreads();
  float r = red4[0] + red4[1] + red4[2] + red4[3];
  __syncthreads();
  return r;
}

__global__ void init_meta_k(int* cnt) {
  if (threadIdx.x < TE) cnt[threadIdx.x] = 0;
}

// ---------------- LN1 fused with split2: hidden -> Apl planes ----------------
__global__ __launch_bounds__(256) void ln1_split_k(const float* __restrict__ in,
                                                   const float* __restrict__ g,
                                                   const float* __restrict__ bb,
                                                   __bf16* __restrict__ P) {
  __shared__ float red4[4];
  const size_t SA = (size_t)TT * TD;
  int row = blockIdx.x, tid = threadIdx.x;
  const float* x = in + (size_t)row * TD;
  float v0 = x[tid], v1 = x[tid + 256], v2 = x[tid + 512];
  float sum = block_sum256(v0 + v1 + v2, red4);
  float mean = sum * (1.0f / 768.0f);
  float d0 = v0 - mean, d1 = v1 - mean, d2 = v2 - mean;
  float var = block_sum256(d0*d0 + d1*d1 + d2*d2, red4) * (1.0f / 768.0f);
  float rs = rsqrtf(var + 1e-12f);
  float xn[3] = { g[tid]       * (d0 * rs) + bb[tid],
                  g[tid + 256] * (d1 * rs) + bb[tid + 256],
                  g[tid + 512] * (d2 * rs) + bb[tid + 512] };
  #pragma unroll
  for (int i = 0; i < 3; ++i) {
    __bf16 h, m; split2(xn[i], h, m);
    size_t o = (size_t)row * TD + tid + 256 * i;
    P[o] = h; P[SA + o] = m;
  }
}

// ---------------- transpose + 2-way split weights ----------------
__global__ void tpose_split2_k(const float* __restrict__ W0, const float* __restrict__ W1,
                               const float* __restrict__ W2,
                               __bf16* __restrict__ BT, size_t SB, int roffmul) {
  __shared__ float tile[32][33];
  const float* W = (blockIdx.z == 0) ? W0 : (blockIdx.z == 1) ? W1 : W2;
  int roff = roffmul * (int)blockIdx.z * TD;
  int c0 = blockIdx.x * 32, r0 = blockIdx.y * 32;
  int tx = threadIdx.x, ty = threadIdx.y;
  #pragma unroll
  for (int i = 0; i < 32; i += 8)
    tile[ty + i][tx] = W[(size_t)(r0 + ty + i) * TD + c0 + tx];
  __syncthreads();
  #pragma unroll
  for (int i = 0; i < 32; i += 8) {
    float x = tile[tx][ty + i];
    __bf16 h, m; split2(x, h, m);
    size_t o = (size_t)(roff + c0 + ty + i) * TD + r0 + tx;
    BT[o] = h; BT[SB + o] = m;
  }
}

// ---------------- split-bf16 4-pass GEMM: (Ah+Am)(Bh+Bm), full cross ----------------
// LDS: row-major [128][32] bf16/plane, 16B granule XOR-swizzled within row-pairs
// (pre-swizzled global source, since global_load_lds dest is linear); reads use
// qs = (q ^ ((lm>>1)&3))*8. 8-way conflict -> free 2-way.
template<int EPI>
__global__ __launch_bounds__(256) void gemm_split4_k(
    const __bf16* __restrict__ A0, const __bf16* __restrict__ A1,
    const __bf16* __restrict__ Bpl, size_t SB,
    const float* __restrict__ bi0, const float* __restrict__ bi1, const float* __restrict__ bi2,
    const float* __restrict__ resid, float* __restrict__ C,
    __bf16* __restrict__ qh_out, __bf16* __restrict__ qm_out, float* __restrict__ vout)
{
  __shared__ __align__(16) __bf16 As[2][4096];
  __shared__ __align__(16) __bf16 Bs[2][4096];
  const __bf16* Ap[2] = {A0, A1};
  int n0 = blockIdx.x * 128, m0 = blockIdx.y * 128;
  int tid = threadIdx.x;
  int wave = tid >> 6, lane = tid & 63;
  int wr = wave >> 1, wc = wave & 1;
  int lm = lane & 15, q = lane >> 4;
  int qs = (q ^ ((lm >> 1) & 3)) * 8;   // swizzled 16B-granule read offset
  f32x4_t acc[4][4];
  #pragma unroll
  for (int i = 0; i < 4; ++i)
    #pragma unroll
    for (int j = 0; j < 4; ++j) { f32x4_t z = {0.f,0.f,0.f,0.f}; acc[i][j] = z; }
  for (int k0 = 0; k0 < TD; k0 += 32) {
    #pragma unroll
    for (int it = 0; it < 2; ++it) {
      int f = it * 256 + tid; int r = f >> 2;
      int c8 = ((f & 3) ^ ((f >> 3) & 3)) * 8;   // pre-swizzled global chunk
      #pragma unroll
      for (int p = 0; p < 2; ++p) {
        async16(Ap[p] + (size_t)(m0 + r) * TD + k0 + c8, &As[p][f * 8]);
        async16(Bpl + p * SB + (size_t)(n0 + r) * TD + k0 + c8, &Bs[p][f * 8]);
      }
    }
    __syncthreads();
    bf16x8_t af[2][4];
    #pragma unroll
    for (int pa = 0; pa < 2; ++pa)
      #pragma unroll
      for (int i = 0; i < 4; ++i)
        af[pa][i] = *(const bf16x8_t*)(&As[pa][(wr*64 + i*16 + lm) * 32 + qs]);
    #pragma unroll
    for (int pb = 0; pb < 2; ++pb) {
      bf16x8_t bfr[4];
      #pragma unroll
      for (int j = 0; j < 4; ++j)
        bfr[j] = *(const bf16x8_t*)(&Bs[pb][(wc*64 + j*16 + lm) * 32 + qs]);
      #pragma unroll
      for (int pa = 0; pa < 2; ++pa)
        #pragma unroll
        for (int i = 0; i < 4; ++i)
          #pragma unroll
          for (int j = 0; j < 4; ++j)
            acc[i][j] = __builtin_amdgcn_mfma_f32_16x16x32_bf16(af[pa][i], bfr[j], acc[i][j], 0, 0, 0);
    }
    __syncthreads();
  }
  #pragma unroll
  for (int i = 0; i < 4; ++i) {
    #pragma unroll
    for (int j = 0; j < 4; ++j) {
      #pragma unroll
      for (int r = 0; r < 4; ++r) {
        int row = m0 + wr*64 + i*16 + q*4 + r;
        int col = n0 + wc*64 + j*16 + lm;
        float v = acc[i][j][r];
        if (EPI == 0) {
          float bias = (col < 768) ? bi0[col] : (col < 1536) ? bi1[col - 768] : bi2[col - 1536];
          v += bias;
          if (col < 768) v *= 0.125f;
          if (col < 1536) {
            __bf16 hh = (__bf16)v; float r1 = v - (float)hh;
            qh_out[(size_t)row * 1536 + col] = hh;
            qm_out[(size_t)row * 1536 + col] = (__bf16)r1;
          } else {
            vout[(size_t)row * TD + (col - 1536)] = v;
          }
        } else {
          v += bi0[col] + resid[(size_t)row * TD + col];
          C[(size_t)row * TD + col] = v;
        }
      }
    }
  }
}

// ---------------- V transpose + split2 ----------------
__global__ void vT_split2_k(const float* __restrict__ vcol,
                            __bf16* __restrict__ v0, __bf16* __restrict__ v1) {
  __shared__ float tile[32][33];
  int s0 = blockIdx.x * 32, d0 = blockIdx.y * 32, bh = blockIdx.z;
  int b = bh / 12, h = bh - b * 12;
  int tx = threadIdx.x, ty = threadIdx.y;
  #pragma unroll
  for (int i = 0; i < 32; i += 8)
    tile[ty + i][tx] = vcol[(size_t)(b * TS + s0 + ty + i) * TD + h * 64 + d0 + tx];
  __syncthreads();
  #pragma unroll
  for (int i = 0; i < 32; i += 8) {
    float x = tile[tx][ty + i];
    __bf16 hh, mm; split2(x, hh, mm);
    size_t o = (size_t)(bh * 64 + d0 + ty + i) * TS + s0 + tx;
    v0[o] = hh; v1[o] = mm;
  }
}

// ---------------- MFMA flash attention (2-plane P/V, 4-pass PV) ----------------
#define AST 72
__global__ __launch_bounds__(256) void attn_mfma_k(
    const __bf16* __restrict__ qkh, const __bf16* __restrict__ qkm,
    const __bf16* __restrict__ vT0, const __bf16* __restrict__ vT1,
    const int* __restrict__ mask,
    __bf16* __restrict__ ch, __bf16* __restrict__ cm)
{
  __shared__ __align__(16) __bf16 KS[2][64 * AST];
  __shared__ __align__(16) __bf16 VS[2][64 * AST];
  __shared__ __align__(16) __bf16 PS[2][64 * AST];
  __shared__ float maskadd[512];
  int qt = blockIdx.x, h = blockIdx.y, b = blockIdx.z;
  int tid = threadIdx.x, w = tid >> 6, lane = tid & 63;
  int lm = lane & 15, quad = lane >> 4;
  int t0 = b * TS, t0q = t0 + qt * 64, bh = b * TNH + h;
  for (int i = tid; i < 512; i += 256)
    maskadd[i] = (mask[t0 + i] != 0) ? 0.0f : -1e30f;
  #pragma unroll
  for (int it = 0; it < 2; ++it) {
    int f = it * 256 + tid, r = f >> 3, c8 = (f & 7) * 8;
    *(uint4*)&PS[0][r * AST + c8] = *(const uint4*)(qkh + (size_t)(t0q + r) * 1536 + h * 64 + c8);
    *(uint4*)&PS[1][r * AST + c8] = *(const uint4*)(qkm + (size_t)(t0q + r) * 1536 + h * 64 + c8);
  }
  __syncthreads();
  bf16x8_t qf[2][2];
  #pragma unroll
  for (int p = 0; p < 2; ++p)
    #pragma unroll
    for (int ks = 0; ks < 2; ++ks)
      qf[p][ks] = *(const bf16x8_t*)&PS[p][(w * 16 + lm) * AST + ks * 32 + quad * 8];
  __syncthreads();
  f32x4_t Oacc[4];
  #pragma unroll
  for (int j = 0; j < 4; ++j) { f32x4_t z = {0.f,0.f,0.f,0.f}; Oacc[j] = z; }
  float mst[4], lst[4];
  #pragma unroll
  for (int r = 0; r < 4; ++r) { mst[r] = -3.0e38f; lst[r] = 0.0f; }

  for (int kc = 0; kc < 8; ++kc) {
    #pragma unroll
    for (int it = 0; it < 2; ++it) {
      int f = it * 256 + tid, r = f >> 3, c8 = (f & 7) * 8;
      size_t ksrc = (size_t)(t0 + kc * 64 + r) * 1536 + 768 + h * 64 + c8;
      *(uint4*)&KS[0][r * AST + c8] = *(const uint4*)(qkh + ksrc);
      *(uint4*)&KS[1][r * AST + c8] = *(const uint4*)(qkm + ksrc);
      size_t vsrc = (size_t)(bh * 64 + r) * TS + kc * 64 + c8;
      *(uint4*)&VS[0][r * AST + c8] = *(const uint4*)(vT0 + vsrc);
      *(uint4*)&VS[1][r * AST + c8] = *(const uint4*)(vT1 + vsrc);
    }
    __syncthreads();
    f32x4_t sacc[4];
    #pragma unroll
    for (int j = 0; j < 4; ++j) { f32x4_t z = {0.f,0.f,0.f,0.f}; sacc[j] = z; }
    #pragma unroll
    for (int ks = 0; ks < 2; ++ks) {
      bf16x8_t kh_[4], km_[4];
      #pragma unroll
      for (int jn = 0; jn < 4; ++jn) {
        kh_[jn] = *(const bf16x8_t*)&KS[0][(jn*16 + lm) * AST + ks*32 + quad*8];
        km_[jn] = *(const bf16x8_t*)&KS[1][(jn*16 + lm) * AST + ks*32 + quad*8];
      }
      #pragma unroll
      for (int jn = 0; jn < 4; ++jn)
        sacc[jn] = __builtin_amdgcn_mfma_f32_16x16x32_bf16(qf[0][ks], kh_[jn], sacc[jn], 0,0,0);
      #pragma unroll
      for (int jn = 0; jn < 4; ++jn)
        sacc[jn] = __builtin_amdgcn_mfma_f32_16x16x32_bf16(qf[0][ks], km_[jn], sacc[jn], 0,0,0);
      #pragma unroll
      for (int jn = 0; jn < 4; ++jn)
        sacc[jn] = __builtin_amdgcn_mfma_f32_16x16x32_bf16(qf[1][ks], kh_[jn], sacc[jn], 0,0,0);
    }
    float s[4][4];
    #pragma unroll
    for (int jn = 0; jn < 4; ++jn)
      #pragma unroll
      for (int r = 0; r < 4; ++r)
        s[jn][r] = sacc[jn][r] + maskadd[kc*64 + jn*16 + lm];
    float alpha[4];
    #pragma unroll
    for (int r = 0; r < 4; ++r) {
      float rmax = fmaxf(fmaxf(s[0][r], s[1][r]), fmaxf(s[2][r], s[3][r]));
      #pragma unroll
      for (int mk = 1; mk < 16; mk <<= 1)
        rmax = fmaxf(rmax, __shfl_xor(rmax, mk, 64));
      float mnew = fmaxf(mst[r], rmax);
      alpha[r] = expf(mst[r] - mnew);
      mst[r] = mnew;
      float psum = 0.0f;
      #pragma unroll
      for (int jn = 0; jn < 4; ++jn) {
        float p = expf(s[jn][r] - mnew);
        s[jn][r] = p;
        psum += p;
      }
      #pragma unroll
      for (int mk = 1; mk < 16; mk <<= 1)
        psum += __shfl_xor(psum, mk, 64);
      lst[r] = lst[r] * alpha[r] + psum;
    }
    #pragma unroll
    for (int jn = 0; jn < 4; ++jn)
      #pragma unroll
      for (int r = 0; r < 4; ++r)
        Oacc[jn][r] *= alpha[r];
    #pragma unroll
    for (int jn = 0; jn < 4; ++jn)
      #pragma unroll
      for (int r = 0; r < 4; ++r) {
        __bf16 ph, pm; split2(s[jn][r], ph, pm);
        int pa = (w*16 + quad*4 + r) * AST + jn*16 + lm;
        PS[0][pa] = ph; PS[1][pa] = pm;
      }
    __syncthreads();
    #pragma unroll
    for (int ks = 0; ks < 2; ++ks) {
      bf16x8_t af[2];
      #pragma unroll
      for (int p = 0; p < 2; ++p)
        af[p] = *(const bf16x8_t*)&PS[p][(w*16 + lm) * AST + ks*32 + quad*8];
      bf16x8_t vf[2][4];
      #pragma unroll
      for (int p = 0; p < 2; ++p)
        #pragma unroll
        for (int jn = 0; jn < 4; ++jn)
          vf[p][jn] = *(const bf16x8_t*)&VS[p][(jn*16 + lm) * AST + ks*32 + quad*8];
      #pragma unroll
      for (int jn = 0; jn < 4; ++jn) {
        Oacc[jn] = __builtin_amdgcn_mfma_f32_16x16x32_bf16(af[0], vf[0][jn], Oacc[jn], 0,0,0);
        Oacc[jn] = __builtin_amdgcn_mfma_f32_16x16x32_bf16(af[0], vf[1][jn], Oacc[jn], 0,0,0);
        Oacc[jn] = __builtin_amdgcn_mfma_f32_16x16x32_bf16(af[1], vf[0][jn], Oacc[jn], 0,0,0);
        Oacc[jn] = __builtin_amdgcn_mfma_f32_16x16x32_bf16(af[1], vf[1][jn], Oacc[jn], 0,0,0);
      }
    }
    __syncthreads();
  }
  float linv[4];
  #pragma unroll
  for (int r = 0; r < 4; ++r) linv[r] = 1.0f / lst[r];
  #pragma unroll
  for (int jn = 0; jn < 4; ++jn)
    #pragma unroll
    for (int r = 0; r < 4; ++r) {
      float o = Oacc[jn][r] * linv[r];
      __bf16 hh, mm; split2(o, hh, mm);
      size_t oo = (size_t)(t0q + w*16 + quad*4 + r) * TD + h*64 + jn*16 + lm;
      ch[oo] = hh; cm[oo] = mm;
    }
}

// ---------------- LN2 + gate (no atomics; routing handled by hist/slot kernels) ----
__global__ __launch_bounds__(256) void ln2_gate_k(const float* __restrict__ attn,
                                                  const float* __restrict__ g,
                                                  const float* __restrict__ bb,
                                                  const float* __restrict__ gw,
                                                  const float* __restrict__ gb,
                                                  __bf16* __restrict__ x2,
                                                  float* __restrict__ gates,
                                                  int* __restrict__ tok_e,
                                                  float* __restrict__ tok_w) {
  __shared__ float red4[4];
  __shared__ float redc[4][7];
  int row = blockIdx.x, tid = threadIdx.x;
  const float* x = attn + (size_t)row * TD;
  float v0 = x[tid], v1 = x[tid + 256], v2 = x[tid + 512];
  float sum = block_sum256(v0 + v1 + v2, red4);
  float mean = sum * (1.0f / 768.0f);
  float d0 = v0 - mean, d1 = v1 - mean, d2 = v2 - mean;
  float var = block_sum256(d0*d0 + d1*d1 + d2*d2, red4) * (1.0f / 768.0f);
  float rs = rsqrtf(var + 1e-12f);
  float xn0 = g[tid]       * (d0 * rs) + bb[tid];
  float xn1 = g[tid + 256] * (d1 * rs) + bb[tid + 256];
  float xn2 = g[tid + 512] * (d2 * rs) + bb[tid + 512];
  __bf16* xo = x2 + (size_t)row * TD;
  xo[tid] = (__bf16)xn0; xo[tid + 256] = (__bf16)xn1; xo[tid + 512] = (__bf16)xn2;
  float p[7];
  const float* w0 = gw + (size_t)tid * 7;
  const float* w1p = gw + (size_t)(tid + 256) * 7;
  const float* w2p = gw + (size_t)(tid + 512) * 7;
  #pragma unroll
  for (int e = 0; e < 7; ++e) p[e] = xn0 * w0[e] + xn1 * w1p[e] + xn2 * w2p[e];
  #pragma unroll
  for (int e = 0; e < 7; ++e)
    #pragma unroll
    for (int o = 32; o > 0; o >>= 1) p[e] += __shfl_down(p[e], o, 64);
  int lane = tid & 63, wv = tid >> 6;
  if (lane == 0) {
    #pragma unroll
    for (int e = 0; e < 7; ++e) redc[wv][e] = p[e];
  }
  __syncthreads();
  if (tid == 0) {
    float l[7];
    #pragma unroll
    for (int e = 0; e < 7; ++e)
      l[e] = redc[0][e] + redc[1][e] + redc[2][e] + redc[3][e] + gb[e];
    int i1 = 0;
    for (int e = 1; e < 7; ++e) if (l[e] > l[i1]) i1 = e;
    int i2 = -1;
    for (int e = 0; e < 7; ++e) if (e != i1 && (i2 < 0 || l[e] > l[i2])) i2 = e;
    float m = l[i1];
    float e1 = expf(l[i1] - m), e2 = expf(l[i2] - m);
    float inv = 1.0f / (e1 + e2);
    float g1 = e1 * inv, g2 = e2 * inv;
    float* go = gates + (size_t)row * 7;
    #pragma unroll
    for (int e = 0; e < 7; ++e) go[e] = 0.0f;
    go[i1] = g1; go[i2] = g2;
    tok_e[row * 2] = i1; tok_e[row * 2 + 1] = i2;
    tok_w[row * 2] = g1; tok_w[row * 2 + 1] = g2;
  }
}

// ---------------- histogram of expert assignments (ballot-aggregated) ----------------
__global__ __launch_bounds__(256) void hist_k(const int* __restrict__ tok_e,
                                              int* __restrict__ cnt) {
  __shared__ int hloc[TE];
  int i = blockIdx.x * 256 + threadIdx.x;
  int e = tok_e[i];
  if (threadIdx.x < TE) hloc[threadIdx.x] = 0;
  __syncthreads();
  #pragma unroll
  for (int ee = 0; ee < TE; ++ee) {
    unsigned long long m = __ballot(e == ee);
    if ((threadIdx.x & 63) == 0 && m) atomicAdd(&hloc[ee], (int)__popcll(m));
  }
  __syncthreads();
  if (threadIdx.x < TE) atomicAdd(&cnt[threadIdx.x], hloc[threadIdx.x]);
}

// ---------------- prefix (parallel rb2e fill) ----------------
__global__ void prefix_k(const int* __restrict__ cnt, int* __restrict__ fill,
                         int* __restrict__ nrb_p, int* __restrict__ rb2e) {
  __shared__ int start[TE + 1];
  if (threadIdx.x == 0) {
    int acc = 0;
    for (int e = 0; e < TE; ++e) {
      start[e] = acc;
      int nb = (cnt[e] + 127) >> 7;
      fill[e] = acc * 128;
      acc += nb;
    }
    start[TE] = acc;
    nrb_p[0] = acc;
  }
  __syncthreads();
  for (int b = threadIdx.x; b < start[TE]; b += blockDim.x) {
    int e = 0;
    while (start[e + 1] <= b) ++e;
    rb2e[b] = e;
  }
}

// ---------------- slot assignment: ballot rank + per-block aggregated atomic ----------------
__global__ __launch_bounds__(256) void slot_assign_k(const int* __restrict__ tok_e,
                                                     const float* __restrict__ tok_w,
                                                     int* __restrict__ fill,
                                                     int* __restrict__ tok_slot,
                                                     float* __restrict__ row_gw) {
  __shared__ int wcnt[4][TE];
  __shared__ int wbase[4][TE];
  int i = blockIdx.x * 256 + threadIdx.x;
  int e = tok_e[i];
  int lane = threadIdx.x & 63, wv = threadIdx.x >> 6;
  unsigned long long lt = (1ULL << lane) - 1ULL;
  int myrank = 0;
  #pragma unroll
  for (int ee = 0; ee < TE; ++ee) {
    unsigned long long m = __ballot(e == ee);
    if (e == ee) myrank = (int)__popcll(m & lt);
    if (lane == 0) wcnt[wv][ee] = (int)__popcll(m);
  }
  __syncthreads();
  if (threadIdx.x < TE) {
    int ee = threadIdx.x;
    int c0 = wcnt[0][ee], c1 = wcnt[1][ee], c2 = wcnt[2][ee], c3 = wcnt[3][ee];
    int base = atomicAdd(&fill[ee], c0 + c1 + c2 + c3);
    wbase[0][ee] = base;
    wbase[1][ee] = base + c0;
    wbase[2][ee] = base + c0 + c1;
    wbase[3][ee] = base + c0 + c1 + c2;
  }
  __syncthreads();
  int slot = wbase[wv][e] + myrank;
  tok_slot[i] = slot;
  row_gw[slot] = tok_w[i];
}

// ---------------- copy token rows to grouped buffer (no atomics) ----------------
__global__ __launch_bounds__(192) void copy_xg_k(const __bf16* __restrict__ x2,
                                                 const int* __restrict__ tok_slot,
                                                 __bf16* __restrict__ xg) {
  int t = blockIdx.x, tid = threadIdx.x;
  int j = tid / 96, c = tid - j * 96;
  int s = tok_slot[t * 2 + j];
  *(uint4*)(xg + (size_t)s * TD + c * 8) =
      *(const uint4*)(x2 + (size_t)t * TD + c * 8);
}

// ---------------- transpose + cast fp32 -> bf16 ----------------
__global__ void transpose_cast_k(const float* __restrict__ in, __bf16* __restrict__ out,
                                 int R, int C) {
  __shared__ float tile[32][33];
  size_t zoff = (size_t)blockIdx.z * R * C;
  const float* ip = in + zoff;
  __bf16* op = out + zoff;
  int c0 = blockIdx.x * 32, r0 = blockIdx.y * 32;
  int tx = threadIdx.x, ty = threadIdx.y;
  #pragma unroll
  for (int i = 0; i < 32; i += 8)
    tile[ty + i][tx] = ip[(size_t)(r0 + ty + i) * C + c0 + tx];
  __syncthreads();
  #pragma unroll
  for (int i = 0; i < 32; i += 8)
    op[(size_t)(c0 + ty + i) * R + r0 + tx] = (__bf16)tile[tx][ty + i];
}

// ================= sparse FFN GEMMs: T3+T4 counted-vmcnt pipeline =================
// Depth-2 prefetch, 3 LDS buffers (a stage never writes a buffer being read),
// raw s_barrier + counted s_waitcnt vmcnt(4) (4 loads/thread/tile; 8 in flight).
// Per iter: each wave waits ITS tile-t loads (vmcnt(4)), barrier => all waves'
// tile-t loads landed; stage tile t+2 into the third buffer; ds_read+MFMA tile t.
// Buffer index is compile-time (groups of 3); stage addresses are incrementing
// per-thread pointers (fixes R4's VALU-bloat regression).

#define FFN_STG(AS, BS, X) do { \
    async16(pA1, &AS[X][tid * 8]);          async16(pB1, &BS[X][tid * 8]); \
    async16(pA2, &AS[X][(256 + tid) * 8]);  async16(pB2, &BS[X][(256 + tid) * 8]); \
    pA1 += 32; pB1 += 32; pA2 += 32; pB2 += 32; \
  } while (0)

#define FFN_COMP(AS, BS, X) do { \
    bf16x8_t af[4], bfr[4]; \
    _Pragma("unroll") \
    for (int i = 0; i < 4; ++i) af[i]  = *(const bf16x8_t*)(&AS[X][(wr*64 + i*16 + lm)*32 + qs]); \
    _Pragma("unroll") \
    for (int j = 0; j < 4; ++j) bfr[j] = *(const bf16x8_t*)(&BS[X][(wc*64 + j*16 + lm)*32 + qs]); \
    _Pragma("unroll") \
    for (int i = 0; i < 4; ++i) \
      _Pragma("unroll") \
      for (int j = 0; j < 4; ++j) \
        acc[i][j] = __builtin_amdgcn_mfma_f32_16x16x32_bf16(af[i], bfr[j], acc[i][j], 0, 0, 0); \
  } while (0)

#define WAITV4 asm volatile("s_waitcnt vmcnt(4)" ::: "memory")
#define WAITV0 asm volatile("s_waitcnt vmcnt(0)" ::: "memory")
#define BAR    __builtin_amdgcn_s_barrier()

// ---------------- sparse FFN GEMM1 ----------------
__global__ __launch_bounds__(256) void gemm1_k(
    const __bf16* __restrict__ xg, const __bf16* __restrict__ w1T,
    const float* __restrict__ b1, const int* __restrict__ rb2e,
    const int* __restrict__ nrb_p, int cb, __bf16* __restrict__ midg)
{
  int rb = cb + blockIdx.y;
  if (rb >= nrb_p[0]) return;
  int e = rb2e[rb];
  __shared__ __align__(16) __bf16 As[3][4096];
  __shared__ __align__(16) __bf16 Bs[3][4096];
  const __bf16* A = xg + (size_t)rb * 128 * TD;
  const __bf16* BT = w1T + (size_t)e * TH * TD;
  const float* be = b1 + (size_t)e * TH;
  int n0 = blockIdx.x * 128;
  int tid = threadIdx.x;
  int wave = tid >> 6, lane = tid & 63;
  int wr = wave >> 1, wc = wave & 1;
  int lm = lane & 15, q = lane >> 4;
  int qs = (q ^ ((lm >> 1) & 3)) * 8;
  f32x4_t acc[4][4];
  #pragma unroll
  for (int i = 0; i < 4; ++i)
    #pragma unroll
    for (int j = 0; j < 4; ++j) { f32x4_t z = {0.f,0.f,0.f,0.f}; acc[i][j] = z; }

  int r_ = tid >> 2;
  int c8_ = ((tid & 3) ^ ((tid >> 3) & 3)) * 8;
  int r2_ = (256 + tid) >> 2;
  int c82_ = (((256 + tid) & 3) ^ (((256 + tid) >> 3) & 3)) * 8;
  const __bf16* pA1 = A + (size_t)r_ * TD + c8_;
  const __bf16* pB1 = BT + (size_t)(n0 + r_) * TD + c8_;
  const __bf16* pA2 = A + (size_t)r2_ * TD + c82_;
  const __bf16* pB2 = BT + (size_t)(n0 + r2_) * TD + c82_;

  const int NT = TD / 32;  // 24, divisible by 3
  FFN_STG(As, Bs, 0);
  FFN_STG(As, Bs, 1);
  for (int t = 0; t < NT - 3; t += 3) {
    WAITV4; BAR; FFN_STG(As, Bs, 2); FFN_COMP(As, Bs, 0);
    WAITV4; BAR; FFN_STG(As, Bs, 0); FFN_COMP(As, Bs, 1);
    WAITV4; BAR; FFN_STG(As, Bs, 1); FFN_COMP(As, Bs, 2);
  }
  WAITV4; BAR; FFN_STG(As, Bs, 2); FFN_COMP(As, Bs, 0);
  WAITV4; BAR; FFN_COMP(As, Bs, 1);
  WAITV0; BAR; FFN_COMP(As, Bs, 2);

  #pragma unroll
  for (int i = 0; i < 4; ++i) {
    #pragma unroll
    for (int j = 0; j < 4; ++j) {
      #pragma unroll
      for (int r = 0; r < 4; ++r) {
        int row = wr*64 + i*16 + q*4 + r;
        int col = n0 + wc*64 + j*16 + lm;
        float v = acc[i][j][r] + be[col];
        v = 0.5f * v * (1.0f + erff(v * 0.70710678118654752f));
        midg[(size_t)(blockIdx.y * 128 + row) * TH + col] = (__bf16)v;
      }
    }
  }
}

// ---------------- sparse FFN GEMM2 ----------------
__global__ __launch_bounds__(256) void gemm2_k(
    const __bf16* __restrict__ midg, const __bf16* __restrict__ w2T,
    const float* __restrict__ b2, const int* __restrict__ rb2e,
    const int* __restrict__ nrb_p, const float* __restrict__ row_gw,
    int cb, __bf16* __restrict__ part)
{
  int rb = cb + blockIdx.y;
  if (rb >= nrb_p[0]) return;
  int e = rb2e[rb];
  __shared__ __align__(16) __bf16 As[3][4096];
  __shared__ __align__(16) __bf16 Bs[3][4096];
  const __bf16* A = midg + (size_t)blockIdx.y * 128 * TH;
  const __bf16* BT = w2T + (size_t)e * TD * TH;
  const float* be = b2 + (size_t)e * TD;
  int n0 = blockIdx.x * 128;
  int tid = threadIdx.x;
  int wave = tid >> 6, lane = tid & 63;
  int wr = wave >> 1, wc = wave & 1;
  int lm = lane & 15, q = lane >> 4;
  int qs = (q ^ ((lm >> 1) & 3)) * 8;
  f32x4_t acc[4][4];
  #pragma unroll
  for (int i = 0; i < 4; ++i)
    #pragma unroll
    for (int j = 0; j < 4; ++j) { f32x4_t z = {0.f,0.f,0.f,0.f}; acc[i][j] = z; }

  int r_ = tid >> 2;
  int c8_ = ((tid & 3) ^ ((tid >> 3) & 3)) * 8;
  int r2_ = (256 + tid) >> 2;
  int c82_ = (((256 + tid) & 3) ^ (((256 + tid) >> 3) & 3)) * 8;
  const __bf16* pA1 = A + (size_t)r_ * TH + c8_;
  const __bf16* pB1 = BT + (size_t)(n0 + r_) * TH + c8_;
  const __bf16* pA2 = A + (size_t)r2_ * TH + c82_;
  const __bf16* pB2 = BT + (size_t)(n0 + r2_) * TH + c82_;

  const int NT = TH / 32;  // 96, divisible by 3
  FFN_STG(As, Bs, 0);
  FFN_STG(As, Bs, 1);
  for (int t = 0; t < NT - 3; t += 3) {
    WAITV4; BAR; FFN_STG(As, Bs, 2); FFN_COMP(As, Bs, 0);
    WAITV4; BAR; FFN_STG(As, Bs, 0); FFN_COMP(As, Bs, 1);
    WAITV4; BAR; FFN_STG(As, Bs, 1); FFN_COMP(As, Bs, 2);
  }
  WAITV4; BAR; FFN_STG(As, Bs, 2); FFN_COMP(As, Bs, 0);
  WAITV4; BAR; FFN_COMP(As, Bs, 1);
  WAITV0; BAR; FFN_COMP(As, Bs, 2);

  #pragma unroll
  for (int i = 0; i < 4; ++i) {
    #pragma unroll
    for (int r = 0; r < 4; ++r) {
      int row = wr*64 + i*16 + q*4 + r;
      int grow = rb * 128 + row;
      float gwt = row_gw[grow];
      #pragma unroll
      for (int j = 0; j < 4; ++j) {
        int col = n0 + wc*64 + j*16 + lm;
        part[(size_t)grow * TD + col] = (__bf16)(gwt * (acc[i][j][r] + be[col]));
      }
    }
  }
}

// ---------------- gather: out[t] += part[slot0] + part[slot1] ----------------
__global__ __launch_bounds__(192) void gather_k(const __bf16* __restrict__ part,
                                                const int* __restrict__ tok_slot,
                                                float* __restrict__ outp) {
  int t = blockIdx.x, tid = threadIdx.x;
  int s0 = tok_slot[t * 2], s1 = tok_slot[t * 2 + 1];
  int c = tid * 4;
  float4 o = *(float4*)(outp + (size_t)t * TD + c);
  bf16x4_t p0 = *(const bf16x4_t*)(part + (size_t)s0 * TD + c);
  bf16x4_t p1 = *(const bf16x4_t*)(part + (size_t)s1 * TD + c);
  o.x += (float)p0[0] + (float)p1[0];
  o.y += (float)p0[1] + (float)p1[1];
  o.z += (float)p0[2] + (float)p1[2];
  o.w += (float)p0[3] + (float)p1[3];
  *(float4*)(outp + (size_t)t * TD + c) = o;
}

// ---------------- host launcher ----------------
extern "C" void kernel_launch(void* const* d_in, const int* in_sizes, int n_in,
                              void* d_out, int out_size, void* d_ws, size_t ws_size,
                              hipStream_t stream) {
  (void)in_sizes; (void)n_in; (void)out_size;
  const float* hidden = (const float*)d_in[0];
  const int*   mask   = (const int*)d_in[1];
  const float* ln1_g  = (const float*)d_in[2];
  const float* ln1_b  = (const float*)d_in[3];
  const float* wq = (const float*)d_in[4];  const float* bq = (const float*)d_in[5];
  const float* wk = (const float*)d_in[6];  const float* bk = (const float*)d_in[7];
  const float* wv = (const float*)d_in[8];  const float* bv = (const float*)d_in[9];
  const float* wo = (const float*)d_in[10]; const float* bo = (const float*)d_in[11];
  const float* gate_w = (const float*)d_in[12];
  const float* gate_b = (const float*)d_in[13];
  const float* w1 = (const float*)d_in[14];
  const float* b1 = (const float*)d_in[15];
  const float* w2 = (const float*)d_in[16];
  const float* b2 = (const float*)d_in[17];
  const float* ln2_g = (const float*)d_in[18];
  const float* ln2_b = (const float*)d_in[19];

  float* outp  = (float*)d_out;
  float* gates = (float*)d_out + (size_t)TT * TD;

  char* ws = (char*)d_ws;
  __bf16* Apl  = (__bf16*)(ws + O_APL);
  __bf16* vT0p = (__bf16*)(ws + O_VT0);
  __bf16* vT1p = (__bf16*)(ws + O_VT1);
  __bf16* ctxh = (__bf16*)(ws + O_CTXH);
  __bf16* ctxm = (__bf16*)(ws + O_CTXM);
  __bf16* qkh  = (__bf16*)(ws + O_QKH);
  __bf16* qkm  = (__bf16*)(ws + O_QKM);
  float*  vcol = (float*)(ws + O_VCOL);
  __bf16* BTp  = (__bf16*)(ws + O_BT);
  __bf16* x2   = (__bf16*)(ws + O_X2);
  __bf16* xg   = (__bf16*)(ws + O_XG);   // also part[] (gemm2 output, after gemm1 consumed xg)
  __bf16* w1T  = (__bf16*)(ws + O_W1T);
  __bf16* w2T  = (__bf16*)(ws + O_W2T);
  char*   meta = ws + O_META;
  int*   cnt      = (int*)(meta + M_CNT);
  int*   fill     = (int*)(meta + M_FILL);
  int*   nrb_p    = (int*)(meta + M_NRB);
  int*   rb2e     = (int*)(meta + M_RB2E);
  int*   tok_e    = (int*)(meta + M_TOKE);
  float* tok_w    = (float*)(meta + M_TOKW);
  float* row_gw   = (float*)(meta + M_RGW);
  int*   tok_slot = (int*)(meta + M_TSLOT);
  __bf16* midg = (__bf16*)(ws + O_MIDG);

  long long midcap = (long long)ws_size - (long long)O_MIDG;
  int crb = (int)(midcap / (128LL * TH * 2));
  if (crb < 1) crb = 1;
  if (crb > NRB_MAX) crb = NRB_MAX;

  const size_t SA = (size_t)TT * TD;

  init_meta_k<<<1, 64, 0, stream>>>(cnt);
  ln1_split_k<<<TT, 256, 0, stream>>>(hidden, ln1_g, ln1_b, Apl);
  tpose_split2_k<<<dim3(24, 24, 3), dim3(32, 8), 0, stream>>>(
      wq, wk, wv, BTp, (size_t)2304 * TD, 1);
  gemm_split4_k<0><<<dim3(18, 64), 256, 0, stream>>>(
      Apl, Apl + SA, BTp, (size_t)2304 * TD,
      bq, bk, bv, nullptr, nullptr, qkh, qkm, vcol);
  vT_split2_k<<<dim3(16, 2, 192), dim3(32, 8), 0, stream>>>(vcol, vT0p, vT1p);
  attn_mfma_k<<<dim3(8, TNH, TB), 256, 0, stream>>>(
      qkh, qkm, vT0p, vT1p, mask, ctxh, ctxm);
  tpose_split2_k<<<dim3(24, 24, 1), dim3(32, 8), 0, stream>>>(
      wo, wo, wo, BTp, (size_t)TD * TD, 0);
  gemm_split4_k<1><<<dim3(6, 64), 256, 0, stream>>>(
      ctxh, ctxm, BTp, (size_t)TD * TD,
      bo, nullptr, nullptr, hidden, outp, nullptr, nullptr, nullptr);
  ln2_gate_k<<<TT, 256, 0, stream>>>(outp, ln2_g, ln2_b, gate_w, gate_b, x2, gates,
                                     tok_e, tok_w);
  hist_k<<<64, 256, 0, stream>>>(tok_e, cnt);
  prefix_k<<<1, 192, 0, stream>>>(cnt, fill, nrb_p, rb2e);
  slot_assign_k<<<64, 256, 0, stream>>>(tok_e, tok_w, fill, tok_slot, row_gw);
  copy_xg_k<<<TT, 192, 0, stream>>>(x2, tok_slot, xg);
  transpose_cast_k<<<dim3(TH / 32, TD / 32, TE), dim3(32, 8), 0, stream>>>(w1, w1T, TD, TH);
  transpose_cast_k<<<dim3(TD / 32, TH / 32, TE), dim3(32, 8), 0, stream>>>(w2, w2T, TH, TD);
  __bf16* part = xg;  // xg rows of chunk c are dead once gemm1(c) has read them
  for (int cb = 0; cb < NRB_MAX; cb += crb) {
    int nb = NRB_MAX - cb; if (nb > crb) nb = crb;
    gemm1_k<<<dim3(TH / 128, nb), 256, 0, stream>>>(xg, w1T, b1, rb2e, nrb_p, cb, midg);
    gemm2_k<<<dim3(TD / 128, nb), 256, 0, stream>>>(midg, w2T, b2, rb2e, nrb_p,
                                                    row_gw, cb, part);
  }
  gather_k<<<TT, 192, 0, stream>>>(part, tok_slot, outp);
}

// Round 6
// 815.457 us; speedup vs baseline: 1.1077x; 1.0874x over previous
//
#include <hip/hip_runtime.h>
#include <hip/hip_bf16.h>
#include <math.h>

#define TB 16
#define TS 512
#define TD 768
#define TH 3072
#define TNH 12
#define TE 7
#define TT (TB*TS)  // 8192 tokens

typedef __bf16 bf16x8_t __attribute__((ext_vector_type(8)));
typedef __bf16 bf16x4_t __attribute__((ext_vector_type(4)));
typedef float f32x4_t __attribute__((ext_vector_type(4)));

#define NEGINF (-__builtin_huge_valf())

// ---- workspace layout (bytes) ----
// split2 everywhere: x = h + m (bf16 planes), residual ~2^-18|x|.
#define O_APL   0ULL
#define O_VT0   0ULL
#define O_VT1   12582912ULL
#define O_CTXH  37748736ULL
#define O_CTXM  50331648ULL
#define O_QKH   62914560ULL
#define O_QKM   88080384ULL
#define O_VCOL  113246208ULL
#define O_BT    138412032ULL
#define O_META  149028864ULL
#define O_MIDG  150077440ULL
#define O_X2    62914560ULL
#define O_XG    75497472ULL   // xg during gemm1; re-used as part[] during gemm2/gather
#define O_W1T   0ULL
#define O_W2T   33030144ULL
// meta sub-offsets
#define M_CNT   0
#define M_FILL  64
#define M_NRB   192
#define M_RB2E  256
#define M_TOKE  1024
#define M_TOKW  66560
#define M_RGW   201216
#define M_TSLOT 270336

#define NRB_MAX 135
#define ROWCAP  17280

// ---------------- async global->LDS 16B ----------------
__device__ __forceinline__ void async16(const void* g, void* l) {
  __builtin_amdgcn_global_load_lds(
      (const __attribute__((address_space(1))) void*)g,
      (__attribute__((address_space(3))) void*)l, 16, 0, 0);
}

// ---------------- 2-way exact bf16 split ----------------
__device__ __forceinline__ void split2(float x, __bf16& h, __bf16& m) {
  h = (__bf16)x;
  m = (__bf16)(x - (float)h);
}

// ---------------- bijective XCD-chunk swizzle (m204) ----------------
// Dispatcher assigns linear block id round-robin to XCDs (xcd = wid%8).
// Remap so each XCD owns a CONTIGUOUS range of work ids: works sharing an
// A-tile (x-fastest order) then hit the same XCD's L2 instead of 6-8 L2s.
__device__ __forceinline__ void xcd_swizzle(int& bx, int& by, int gx, int gy) {
  int nwg = gx * gy;
  int wid = bx + by * gx;
  int q = nwg >> 3, r = nwg & 7;
  int xcd = wid & 7, pos = wid >> 3;
  int work = (xcd < r) ? xcd * (q + 1) + pos
                       : r * (q + 1) + (xcd - r) * q + pos;
  bx = work % gx;
  by = work / gx;
}

// ---------------- block reduction helper ----------------
__device__ __forceinline__ float block_sum256(float v, float* red4) {
  #pragma unroll
  for (int o = 32; o > 0; o >>= 1) v += __shfl_down(v, o, 64);
  int lane = threadIdx.x & 63, wv = threadIdx.x >> 6;
  if (lane == 0) red4[wv] = v;
  __syncthreads();
  float r = red4[0] + red4[1] + red4[2] + red4[3];
  __syncthreads();
  return r;
}

__global__ void init_meta_k(int* cnt) {
  if (threadIdx.x < TE) cnt[threadIdx.x] = 0;
}

// ---------------- LN1 fused with split2: hidden -> Apl planes ----------------
__global__ __launch_bounds__(256) void ln1_split_k(const float* __restrict__ in,
                                                   const float* __restrict__ g,
                                                   const float* __restrict__ bb,
                                                   __bf16* __restrict__ P) {
  __shared__ float red4[4];
  const size_t SA = (size_t)TT * TD;
  int row = blockIdx.x, tid = threadIdx.x;
  const float* x = in + (size_t)row * TD;
  float v0 = x[tid], v1 = x[tid + 256], v2 = x[tid + 512];
  float sum = block_sum256(v0 + v1 + v2, red4);
  float mean = sum * (1.0f / 768.0f);
  float d0 = v0 - mean, d1 = v1 - mean, d2 = v2 - mean;
  float var = block_sum256(d0*d0 + d1*d1 + d2*d2, red4) * (1.0f / 768.0f);
  float rs = rsqrtf(var + 1e-12f);
  float xn[3] = { g[tid]       * (d0 * rs) + bb[tid],
                  g[tid + 256] * (d1 * rs) + bb[tid + 256],
                  g[tid + 512] * (d2 * rs) + bb[tid + 512] };
  #pragma unroll
  for (int i = 0; i < 3; ++i) {
    __bf16 h, m; split2(xn[i], h, m);
    size_t o = (size_t)row * TD + tid + 256 * i;
    P[o] = h; P[SA + o] = m;
  }
}

// ---------------- transpose + 2-way split weights ----------------
__global__ void tpose_split2_k(const float* __restrict__ W0, const float* __restrict__ W1,
                               const float* __restrict__ W2,
                               __bf16* __restrict__ BT, size_t SB, int roffmul) {
  __shared__ float tile[32][33];
  const float* W = (blockIdx.z == 0) ? W0 : (blockIdx.z == 1) ? W1 : W2;
  int roff = roffmul * (int)blockIdx.z * TD;
  int c0 = blockIdx.x * 32, r0 = blockIdx.y * 32;
  int tx = threadIdx.x, ty = threadIdx.y;
  #pragma unroll
  for (int i = 0; i < 32; i += 8)
    tile[ty + i][tx] = W[(size_t)(r0 + ty + i) * TD + c0 + tx];
  __syncthreads();
  #pragma unroll
  for (int i = 0; i < 32; i += 8) {
    float x = tile[tx][ty + i];
    __bf16 h, m; split2(x, h, m);
    size_t o = (size_t)(roff + c0 + ty + i) * TD + r0 + tx;
    BT[o] = h; BT[SB + o] = m;
  }
}

// ---------------- split-bf16 3-pass GEMM: Ah·Bh + Am·Bh + Ah·Bm ----------------
// (Am·Bm dropped: ~2^-18 relative, same order as the split2 truncation itself.)
// LDS: row-major [128][32] bf16/plane, 16B granule XOR-swizzled within row-pairs
// (pre-swizzled global source, since global_load_lds dest is linear); reads use
// qs = (q ^ ((lm>>1)&3))*8. 8-way conflict -> free 2-way.
template<int EPI>
__global__ __launch_bounds__(256) void gemm_split4_k(
    const __bf16* __restrict__ A0, const __bf16* __restrict__ A1,
    const __bf16* __restrict__ Bpl, size_t SB,
    const float* __restrict__ bi0, const float* __restrict__ bi1, const float* __restrict__ bi2,
    const float* __restrict__ resid, float* __restrict__ C,
    __bf16* __restrict__ qh_out, __bf16* __restrict__ qm_out, float* __restrict__ vout)
{
  __shared__ __align__(16) __bf16 As[2][4096];
  __shared__ __align__(16) __bf16 Bs[2][4096];
  const __bf16* Ap[2] = {A0, A1};
  int bx = blockIdx.x, by = blockIdx.y;
  xcd_swizzle(bx, by, gridDim.x, gridDim.y);
  int n0 = bx * 128, m0 = by * 128;
  int tid = threadIdx.x;
  int wave = tid >> 6, lane = tid & 63;
  int wr = wave >> 1, wc = wave & 1;
  int lm = lane & 15, q = lane >> 4;
  int qs = (q ^ ((lm >> 1) & 3)) * 8;   // swizzled 16B-granule read offset
  f32x4_t acc[4][4];
  #pragma unroll
  for (int i = 0; i < 4; ++i)
    #pragma unroll
    for (int j = 0; j < 4; ++j) { f32x4_t z = {0.f,0.f,0.f,0.f}; acc[i][j] = z; }
  for (int k0 = 0; k0 < TD; k0 += 32) {
    #pragma unroll
    for (int it = 0; it < 2; ++it) {
      int f = it * 256 + tid; int r = f >> 2;
      int c8 = ((f & 3) ^ ((f >> 3) & 3)) * 8;   // pre-swizzled global chunk
      #pragma unroll
      for (int p = 0; p < 2; ++p) {
        async16(Ap[p] + (size_t)(m0 + r) * TD + k0 + c8, &As[p][f * 8]);
        async16(Bpl + p * SB + (size_t)(n0 + r) * TD + k0 + c8, &Bs[p][f * 8]);
      }
    }
    __syncthreads();
    bf16x8_t af[2][4];
    #pragma unroll
    for (int pa = 0; pa < 2; ++pa)
      #pragma unroll
      for (int i = 0; i < 4; ++i)
        af[pa][i] = *(const bf16x8_t*)(&As[pa][(wr*64 + i*16 + lm) * 32 + qs]);
    #pragma unroll
    for (int pb = 0; pb < 2; ++pb) {
      bf16x8_t bfr[4];
      #pragma unroll
      for (int j = 0; j < 4; ++j)
        bfr[j] = *(const bf16x8_t*)(&Bs[pb][(wc*64 + j*16 + lm) * 32 + qs]);
      #pragma unroll
      for (int pa = 0; pa < 2 - pb; ++pa)   // hh, mh, hm (mm dropped)
        #pragma unroll
        for (int i = 0; i < 4; ++i)
          #pragma unroll
          for (int j = 0; j < 4; ++j)
            acc[i][j] = __builtin_amdgcn_mfma_f32_16x16x32_bf16(af[pa][i], bfr[j], acc[i][j], 0, 0, 0);
    }
    __syncthreads();
  }
  #pragma unroll
  for (int i = 0; i < 4; ++i) {
    #pragma unroll
    for (int j = 0; j < 4; ++j) {
      #pragma unroll
      for (int r = 0; r < 4; ++r) {
        int row = m0 + wr*64 + i*16 + q*4 + r;
        int col = n0 + wc*64 + j*16 + lm;
        float v = acc[i][j][r];
        if (EPI == 0) {
          float bias = (col < 768) ? bi0[col] : (col < 1536) ? bi1[col - 768] : bi2[col - 1536];
          v += bias;
          if (col < 768) v *= 0.125f;
          if (col < 1536) {
            __bf16 hh = (__bf16)v; float r1 = v - (float)hh;
            qh_out[(size_t)row * 1536 + col] = hh;
            qm_out[(size_t)row * 1536 + col] = (__bf16)r1;
          } else {
            vout[(size_t)row * TD + (col - 1536)] = v;
          }
        } else {
          v += bi0[col] + resid[(size_t)row * TD + col];
          C[(size_t)row * TD + col] = v;
        }
      }
    }
  }
}

// ---------------- V transpose + split2 ----------------
__global__ void vT_split2_k(const float* __restrict__ vcol,
                            __bf16* __restrict__ v0, __bf16* __restrict__ v1) {
  __shared__ float tile[32][33];
  int s0 = blockIdx.x * 32, d0 = blockIdx.y * 32, bh = blockIdx.z;
  int b = bh / 12, h = bh - b * 12;
  int tx = threadIdx.x, ty = threadIdx.y;
  #pragma unroll
  for (int i = 0; i < 32; i += 8)
    tile[ty + i][tx] = vcol[(size_t)(b * TS + s0 + ty + i) * TD + h * 64 + d0 + tx];
  __syncthreads();
  #pragma unroll
  for (int i = 0; i < 32; i += 8) {
    float x = tile[tx][ty + i];
    __bf16 hh, mm; split2(x, hh, mm);
    size_t o = (size_t)(bh * 64 + d0 + ty + i) * TS + s0 + tx;
    v0[o] = hh; v1[o] = mm;
  }
}

// ---------------- MFMA flash attention (2-plane P/V, 3-pass PV) ----------------
#define AST 72
__global__ __launch_bounds__(256) void attn_mfma_k(
    const __bf16* __restrict__ qkh, const __bf16* __restrict__ qkm,
    const __bf16* __restrict__ vT0, const __bf16* __restrict__ vT1,
    const int* __restrict__ mask,
    __bf16* __restrict__ ch, __bf16* __restrict__ cm)
{
  __shared__ __align__(16) __bf16 KS[2][64 * AST];
  __shared__ __align__(16) __bf16 VS[2][64 * AST];
  __shared__ __align__(16) __bf16 PS[2][64 * AST];
  __shared__ float maskadd[512];
  int qt = blockIdx.x, h = blockIdx.y, b = blockIdx.z;
  int tid = threadIdx.x, w = tid >> 6, lane = tid & 63;
  int lm = lane & 15, quad = lane >> 4;
  int t0 = b * TS, t0q = t0 + qt * 64, bh = b * TNH + h;
  for (int i = tid; i < 512; i += 256)
    maskadd[i] = (mask[t0 + i] != 0) ? 0.0f : -1e30f;
  #pragma unroll
  for (int it = 0; it < 2; ++it) {
    int f = it * 256 + tid, r = f >> 3, c8 = (f & 7) * 8;
    *(uint4*)&PS[0][r * AST + c8] = *(const uint4*)(qkh + (size_t)(t0q + r) * 1536 + h * 64 + c8);
    *(uint4*)&PS[1][r * AST + c8] = *(const uint4*)(qkm + (size_t)(t0q + r) * 1536 + h * 64 + c8);
  }
  __syncthreads();
  bf16x8_t qf[2][2];
  #pragma unroll
  for (int p = 0; p < 2; ++p)
    #pragma unroll
    for (int ks = 0; ks < 2; ++ks)
      qf[p][ks] = *(const bf16x8_t*)&PS[p][(w * 16 + lm) * AST + ks * 32 + quad * 8];
  __syncthreads();
  f32x4_t Oacc[4];
  #pragma unroll
  for (int j = 0; j < 4; ++j) { f32x4_t z = {0.f,0.f,0.f,0.f}; Oacc[j] = z; }
  float mst[4], lst[4];
  #pragma unroll
  for (int r = 0; r < 4; ++r) { mst[r] = -3.0e38f; lst[r] = 0.0f; }

  for (int kc = 0; kc < 8; ++kc) {
    #pragma unroll
    for (int it = 0; it < 2; ++it) {
      int f = it * 256 + tid, r = f >> 3, c8 = (f & 7) * 8;
      size_t ksrc = (size_t)(t0 + kc * 64 + r) * 1536 + 768 + h * 64 + c8;
      *(uint4*)&KS[0][r * AST + c8] = *(const uint4*)(qkh + ksrc);
      *(uint4*)&KS[1][r * AST + c8] = *(const uint4*)(qkm + ksrc);
      size_t vsrc = (size_t)(bh * 64 + r) * TS + kc * 64 + c8;
      *(uint4*)&VS[0][r * AST + c8] = *(const uint4*)(vT0 + vsrc);
      *(uint4*)&VS[1][r * AST + c8] = *(const uint4*)(vT1 + vsrc);
    }
    __syncthreads();
    f32x4_t sacc[4];
    #pragma unroll
    for (int j = 0; j < 4; ++j) { f32x4_t z = {0.f,0.f,0.f,0.f}; sacc[j] = z; }
    #pragma unroll
    for (int ks = 0; ks < 2; ++ks) {
      bf16x8_t kh_[4], km_[4];
      #pragma unroll
      for (int jn = 0; jn < 4; ++jn) {
        kh_[jn] = *(const bf16x8_t*)&KS[0][(jn*16 + lm) * AST + ks*32 + quad*8];
        km_[jn] = *(const bf16x8_t*)&KS[1][(jn*16 + lm) * AST + ks*32 + quad*8];
      }
      #pragma unroll
      for (int jn = 0; jn < 4; ++jn)
        sacc[jn] = __builtin_amdgcn_mfma_f32_16x16x32_bf16(qf[0][ks], kh_[jn], sacc[jn], 0,0,0);
      #pragma unroll
      for (int jn = 0; jn < 4; ++jn)
        sacc[jn] = __builtin_amdgcn_mfma_f32_16x16x32_bf16(qf[0][ks], km_[jn], sacc[jn], 0,0,0);
      #pragma unroll
      for (int jn = 0; jn < 4; ++jn)
        sacc[jn] = __builtin_amdgcn_mfma_f32_16x16x32_bf16(qf[1][ks], kh_[jn], sacc[jn], 0,0,0);
    }
    float s[4][4];
    #pragma unroll
    for (int jn = 0; jn < 4; ++jn)
      #pragma unroll
      for (int r = 0; r < 4; ++r)
        s[jn][r] = sacc[jn][r] + maskadd[kc*64 + jn*16 + lm];
    float alpha[4];
    #pragma unroll
    for (int r = 0; r < 4; ++r) {
      float rmax = fmaxf(fmaxf(s[0][r], s[1][r]), fmaxf(s[2][r], s[3][r]));
      #pragma unroll
      for (int mk = 1; mk < 16; mk <<= 1)
        rmax = fmaxf(rmax, __shfl_xor(rmax, mk, 64));
      float mnew = fmaxf(mst[r], rmax);
      alpha[r] = expf(mst[r] - mnew);
      mst[r] = mnew;
      float psum = 0.0f;
      #pragma unroll
      for (int jn = 0; jn < 4; ++jn) {
        float p = expf(s[jn][r] - mnew);
        s[jn][r] = p;
        psum += p;
      }
      #pragma unroll
      for (int mk = 1; mk < 16; mk <<= 1)
        psum += __shfl_xor(psum, mk, 64);
      lst[r] = lst[r] * alpha[r] + psum;
    }
    #pragma unroll
    for (int jn = 0; jn < 4; ++jn)
      #pragma unroll
      for (int r = 0; r < 4; ++r)
        Oacc[jn][r] *= alpha[r];
    #pragma unroll
    for (int jn = 0; jn < 4; ++jn)
      #pragma unroll
      for (int r = 0; r < 4; ++r) {
        __bf16 ph, pm; split2(s[jn][r], ph, pm);
        int pa = (w*16 + quad*4 + r) * AST + jn*16 + lm;
        PS[0][pa] = ph; PS[1][pa] = pm;
      }
    __syncthreads();
    #pragma unroll
    for (int ks = 0; ks < 2; ++ks) {
      bf16x8_t af[2];
      #pragma unroll
      for (int p = 0; p < 2; ++p)
        af[p] = *(const bf16x8_t*)&PS[p][(w*16 + lm) * AST + ks*32 + quad*8];
      bf16x8_t vf[2][4];
      #pragma unroll
      for (int p = 0; p < 2; ++p)
        #pragma unroll
        for (int jn = 0; jn < 4; ++jn)
          vf[p][jn] = *(const bf16x8_t*)&VS[p][(jn*16 + lm) * AST + ks*32 + quad*8];
      #pragma unroll
      for (int jn = 0; jn < 4; ++jn) {
        Oacc[jn] = __builtin_amdgcn_mfma_f32_16x16x32_bf16(af[0], vf[0][jn], Oacc[jn], 0,0,0);
        Oacc[jn] = __builtin_amdgcn_mfma_f32_16x16x32_bf16(af[0], vf[1][jn], Oacc[jn], 0,0,0);
        Oacc[jn] = __builtin_amdgcn_mfma_f32_16x16x32_bf16(af[1], vf[0][jn], Oacc[jn], 0,0,0);
        // Pm·Vm dropped (~2^-18 relative)
      }
    }
    __syncthreads();
  }
  float linv[4];
  #pragma unroll
  for (int r = 0; r < 4; ++r) linv[r] = 1.0f / lst[r];
  #pragma unroll
  for (int jn = 0; jn < 4; ++jn)
    #pragma unroll
    for (int r = 0; r < 4; ++r) {
      float o = Oacc[jn][r] * linv[r];
      __bf16 hh, mm; split2(o, hh, mm);
      size_t oo = (size_t)(t0q + w*16 + quad*4 + r) * TD + h*64 + jn*16 + lm;
      ch[oo] = hh; cm[oo] = mm;
    }
}

// ---------------- LN2 + gate (no atomics; routing handled by hist/slot kernels) ----
__global__ __launch_bounds__(256) void ln2_gate_k(const float* __restrict__ attn,
                                                  const float* __restrict__ g,
                                                  const float* __restrict__ bb,
                                                  const float* __restrict__ gw,
                                                  const float* __restrict__ gb,
                                                  __bf16* __restrict__ x2,
                                                  float* __restrict__ gates,
                                                  int* __restrict__ tok_e,
                                                  float* __restrict__ tok_w) {
  __shared__ float red4[4];
  __shared__ float redc[4][7];
  int row = blockIdx.x, tid = threadIdx.x;
  const float* x = attn + (size_t)row * TD;
  float v0 = x[tid], v1 = x[tid + 256], v2 = x[tid + 512];
  float sum = block_sum256(v0 + v1 + v2, red4);
  float mean = sum * (1.0f / 768.0f);
  float d0 = v0 - mean, d1 = v1 - mean, d2 = v2 - mean;
  float var = block_sum256(d0*d0 + d1*d1 + d2*d2, red4) * (1.0f / 768.0f);
  float rs = rsqrtf(var + 1e-12f);
  float xn0 = g[tid]       * (d0 * rs) + bb[tid];
  float xn1 = g[tid + 256] * (d1 * rs) + bb[tid + 256];
  float xn2 = g[tid + 512] * (d2 * rs) + bb[tid + 512];
  __bf16* xo = x2 + (size_t)row * TD;
  xo[tid] = (__bf16)xn0; xo[tid + 256] = (__bf16)xn1; xo[tid + 512] = (__bf16)xn2;
  float p[7];
  const float* w0 = gw + (size_t)tid * 7;
  const float* w1p = gw + (size_t)(tid + 256) * 7;
  const float* w2p = gw + (size_t)(tid + 512) * 7;
  #pragma unroll
  for (int e = 0; e < 7; ++e) p[e] = xn0 * w0[e] + xn1 * w1p[e] + xn2 * w2p[e];
  #pragma unroll
  for (int e = 0; e < 7; ++e)
    #pragma unroll
    for (int o = 32; o > 0; o >>= 1) p[e] += __shfl_down(p[e], o, 64);
  int lane = tid & 63, wv = tid >> 6;
  if (lane == 0) {
    #pragma unroll
    for (int e = 0; e < 7; ++e) redc[wv][e] = p[e];
  }
  __syncthreads();
  if (tid == 0) {
    float l[7];
    #pragma unroll
    for (int e = 0; e < 7; ++e)
      l[e] = redc[0][e] + redc[1][e] + redc[2][e] + redc[3][e] + gb[e];
    int i1 = 0;
    for (int e = 1; e < 7; ++e) if (l[e] > l[i1]) i1 = e;
    int i2 = -1;
    for (int e = 0; e < 7; ++e) if (e != i1 && (i2 < 0 || l[e] > l[i2])) i2 = e;
    float m = l[i1];
    float e1 = expf(l[i1] - m), e2 = expf(l[i2] - m);
    float inv = 1.0f / (e1 + e2);
    float g1 = e1 * inv, g2 = e2 * inv;
    float* go = gates + (size_t)row * 7;
    #pragma unroll
    for (int e = 0; e < 7; ++e) go[e] = 0.0f;
    go[i1] = g1; go[i2] = g2;
    tok_e[row * 2] = i1; tok_e[row * 2 + 1] = i2;
    tok_w[row * 2] = g1; tok_w[row * 2 + 1] = g2;
  }
}

// ---------------- histogram of expert assignments (ballot-aggregated) ----------------
__global__ __launch_bounds__(256) void hist_k(const int* __restrict__ tok_e,
                                              int* __restrict__ cnt) {
  __shared__ int hloc[TE];
  int i = blockIdx.x * 256 + threadIdx.x;
  int e = tok_e[i];
  if (threadIdx.x < TE) hloc[threadIdx.x] = 0;
  __syncthreads();
  #pragma unroll
  for (int ee = 0; ee < TE; ++ee) {
    unsigned long long m = __ballot(e == ee);
    if ((threadIdx.x & 63) == 0 && m) atomicAdd(&hloc[ee], (int)__popcll(m));
  }
  __syncthreads();
  if (threadIdx.x < TE) atomicAdd(&cnt[threadIdx.x], hloc[threadIdx.x]);
}

// ---------------- prefix (parallel rb2e fill) ----------------
__global__ void prefix_k(const int* __restrict__ cnt, int* __restrict__ fill,
                         int* __restrict__ nrb_p, int* __restrict__ rb2e) {
  __shared__ int start[TE + 1];
  if (threadIdx.x == 0) {
    int acc = 0;
    for (int e = 0; e < TE; ++e) {
      start[e] = acc;
      int nb = (cnt[e] + 127) >> 7;
      fill[e] = acc * 128;
      acc += nb;
    }
    start[TE] = acc;
    nrb_p[0] = acc;
  }
  __syncthreads();
  for (int b = threadIdx.x; b < start[TE]; b += blockDim.x) {
    int e = 0;
    while (start[e + 1] <= b) ++e;
    rb2e[b] = e;
  }
}

// ---------------- slot assignment: ballot rank + per-block aggregated atomic ----------------
__global__ __launch_bounds__(256) void slot_assign_k(const int* __restrict__ tok_e,
                                                     const float* __restrict__ tok_w,
                                                     int* __restrict__ fill,
                                                     int* __restrict__ tok_slot,
                                                     float* __restrict__ row_gw) {
  __shared__ int wcnt[4][TE];
  __shared__ int wbase[4][TE];
  int i = blockIdx.x * 256 + threadIdx.x;
  int e = tok_e[i];
  int lane = threadIdx.x & 63, wv = threadIdx.x >> 6;
  unsigned long long lt = (1ULL << lane) - 1ULL;
  int myrank = 0;
  #pragma unroll
  for (int ee = 0; ee < TE; ++ee) {
    unsigned long long m = __ballot(e == ee);
    if (e == ee) myrank = (int)__popcll(m & lt);
    if (lane == 0) wcnt[wv][ee] = (int)__popcll(m);
  }
  __syncthreads();
  if (threadIdx.x < TE) {
    int ee = threadIdx.x;
    int c0 = wcnt[0][ee], c1 = wcnt[1][ee], c2 = wcnt[2][ee], c3 = wcnt[3][ee];
    int base = atomicAdd(&fill[ee], c0 + c1 + c2 + c3);
    wbase[0][ee] = base;
    wbase[1][ee] = base + c0;
    wbase[2][ee] = base + c0 + c1;
    wbase[3][ee] = base + c0 + c1 + c2;
  }
  __syncthreads();
  int slot = wbase[wv][e] + myrank;
  tok_slot[i] = slot;
  row_gw[slot] = tok_w[i];
}

// ---------------- copy token rows to grouped buffer (no atomics) ----------------
__global__ __launch_bounds__(192) void copy_xg_k(const __bf16* __restrict__ x2,
                                                 const int* __restrict__ tok_slot,
                                                 __bf16* __restrict__ xg) {
  int t = blockIdx.x, tid = threadIdx.x;
  int j = tid / 96, c = tid - j * 96;
  int s = tok_slot[t * 2 + j];
  *(uint4*)(xg + (size_t)s * TD + c * 8) =
      *(const uint4*)(x2 + (size_t)t * TD + c * 8);
}

// ---------------- transpose + cast fp32 -> bf16 ----------------
__global__ void transpose_cast_k(const float* __restrict__ in, __bf16* __restrict__ out,
                                 int R, int C) {
  __shared__ float tile[32][33];
  size_t zoff = (size_t)blockIdx.z * R * C;
  const float* ip = in + zoff;
  __bf16* op = out + zoff;
  int c0 = blockIdx.x * 32, r0 = blockIdx.y * 32;
  int tx = threadIdx.x, ty = threadIdx.y;
  #pragma unroll
  for (int i = 0; i < 32; i += 8)
    tile[ty + i][tx] = ip[(size_t)(r0 + ty + i) * C + c0 + tx];
  __syncthreads();
  #pragma unroll
  for (int i = 0; i < 32; i += 8)
    op[(size_t)(c0 + ty + i) * R + r0 + tx] = (__bf16)tile[tx][ty + i];
}

// ---------------- sparse FFN GEMM1 (R3 structure + XCD swizzle) ----------------
__global__ __launch_bounds__(256) void gemm1_k(
    const __bf16* __restrict__ xg, const __bf16* __restrict__ w1T,
    const float* __restrict__ b1, const int* __restrict__ rb2e,
    const int* __restrict__ nrb_p, int cb, __bf16* __restrict__ midg)
{
  int bx = blockIdx.x, by = blockIdx.y;
  xcd_swizzle(bx, by, gridDim.x, gridDim.y);
  int rb = cb + by;
  if (rb >= nrb_p[0]) return;
  int e = rb2e[rb];
  __shared__ __align__(16) __bf16 As[4096];
  __shared__ __align__(16) __bf16 Bs[4096];
  const __bf16* A = xg + (size_t)rb * 128 * TD;
  const __bf16* BT = w1T + (size_t)e * TH * TD;
  const float* be = b1 + (size_t)e * TH;
  int n0 = bx * 128;
  int tid = threadIdx.x;
  int wave = tid >> 6, lane = tid & 63;
  int wr = wave >> 1, wc = wave & 1;
  int lm = lane & 15, q = lane >> 4;
  int qs = (q ^ ((lm >> 1) & 3)) * 8;
  f32x4_t acc[4][4];
  #pragma unroll
  for (int i = 0; i < 4; ++i)
    #pragma unroll
    for (int j = 0; j < 4; ++j) { f32x4_t z = {0.f,0.f,0.f,0.f}; acc[i][j] = z; }
  for (int k0 = 0; k0 < TD; k0 += 32) {
    #pragma unroll
    for (int it = 0; it < 2; ++it) {
      int f = it * 256 + tid; int r = f >> 2;
      int c8 = ((f & 3) ^ ((f >> 3) & 3)) * 8;
      async16(A + (size_t)r * TD + k0 + c8, &As[f * 8]);
      async16(BT + (size_t)(n0 + r) * TD + k0 + c8, &Bs[f * 8]);
    }
    __syncthreads();
    bf16x8_t af[4], bfr[4];
    #pragma unroll
    for (int i = 0; i < 4; ++i) af[i]  = *(const bf16x8_t*)(&As[(wr*64 + i*16 + lm)*32 + qs]);
    #pragma unroll
    for (int j = 0; j < 4; ++j) bfr[j] = *(const bf16x8_t*)(&Bs[(wc*64 + j*16 + lm)*32 + qs]);
    #pragma unroll
    for (int i = 0; i < 4; ++i)
      #pragma unroll
      for (int j = 0; j < 4; ++j)
        acc[i][j] = __builtin_amdgcn_mfma_f32_16x16x32_bf16(af[i], bfr[j], acc[i][j], 0, 0, 0);
    __syncthreads();
  }
  #pragma unroll
  for (int i = 0; i < 4; ++i) {
    #pragma unroll
    for (int j = 0; j < 4; ++j) {
      #pragma unroll
      for (int r = 0; r < 4; ++r) {
        int row = wr*64 + i*16 + q*4 + r;
        int col = n0 + wc*64 + j*16 + lm;
        float v = acc[i][j][r] + be[col];
        v = 0.5f * v * (1.0f + erff(v * 0.70710678118654752f));
        midg[(size_t)(by * 128 + row) * TH + col] = (__bf16)v;
      }
    }
  }
}

// ---------------- sparse FFN GEMM2 (R3 structure + XCD swizzle) ----------------
__global__ __launch_bounds__(256) void gemm2_k(
    const __bf16* __restrict__ midg, const __bf16* __restrict__ w2T,
    const float* __restrict__ b2, const int* __restrict__ rb2e,
    const int* __restrict__ nrb_p, const float* __restrict__ row_gw,
    int cb, __bf16* __restrict__ part)
{
  int bx = blockIdx.x, by = blockIdx.y;
  xcd_swizzle(bx, by, gridDim.x, gridDim.y);
  int rb = cb + by;
  if (rb >= nrb_p[0]) return;
  int e = rb2e[rb];
  __shared__ __align__(16) __bf16 As[4096];
  __shared__ __align__(16) __bf16 Bs[4096];
  const __bf16* A = midg + (size_t)by * 128 * TH;
  const __bf16* BT = w2T + (size_t)e * TD * TH;
  const float* be = b2 + (size_t)e * TD;
  int n0 = bx * 128;
  int tid = threadIdx.x;
  int wave = tid >> 6, lane = tid & 63;
  int wr = wave >> 1, wc = wave & 1;
  int lm = lane & 15, q = lane >> 4;
  int qs = (q ^ ((lm >> 1) & 3)) * 8;
  f32x4_t acc[4][4];
  #pragma unroll
  for (int i = 0; i < 4; ++i)
    #pragma unroll
    for (int j = 0; j < 4; ++j) { f32x4_t z = {0.f,0.f,0.f,0.f}; acc[i][j] = z; }
  for (int k0 = 0; k0 < TH; k0 += 32) {
    #pragma unroll
    for (int it = 0; it < 2; ++it) {
      int f = it * 256 + tid; int r = f >> 2;
      int c8 = ((f & 3) ^ ((f >> 3) & 3)) * 8;
      async16(A + (size_t)r * TH + k0 + c8, &As[f * 8]);
      async16(BT + (size_t)(n0 + r) * TH + k0 + c8, &Bs[f * 8]);
    }
    __syncthreads();
    bf16x8_t af[4], bfr[4];
    #pragma unroll
    for (int i = 0; i < 4; ++i) af[i]  = *(const bf16x8_t*)(&As[(wr*64 + i*16 + lm)*32 + qs]);
    #pragma unroll
    for (int j = 0; j < 4; ++j) bfr[j] = *(const bf16x8_t*)(&Bs[(wc*64 + j*16 + lm)*32 + qs]);
    #pragma unroll
    for (int i = 0; i < 4; ++i)
      #pragma unroll
      for (int j = 0; j < 4; ++j)
        acc[i][j] = __builtin_amdgcn_mfma_f32_16x16x32_bf16(af[i], bfr[j], acc[i][j], 0, 0, 0);
    __syncthreads();
  }
  #pragma unroll
  for (int i = 0; i < 4; ++i) {
    #pragma unroll
    for (int r = 0; r < 4; ++r) {
      int row = wr*64 + i*16 + q*4 + r;
      int grow = rb * 128 + row;
      float gwt = row_gw[grow];
      #pragma unroll
      for (int j = 0; j < 4; ++j) {
        int col = n0 + wc*64 + j*16 + lm;
        part[(size_t)grow * TD + col] = (__bf16)(gwt * (acc[i][j][r] + be[col]));
      }
    }
  }
}

// ---------------- gather: out[t] += part[slot0] + part[slot1] ----------------
__global__ __launch_bounds__(192) void gather_k(const __bf16* __restrict__ part,
                                                const int* __restrict__ tok_slot,
                                                float* __restrict__ outp) {
  int t = blockIdx.x, tid = threadIdx.x;
  int s0 = tok_slot[t * 2], s1 = tok_slot[t * 2 + 1];
  int c = tid * 4;
  float4 o = *(float4*)(outp + (size_t)t * TD + c);
  bf16x4_t p0 = *(const bf16x4_t*)(part + (size_t)s0 * TD + c);
  bf16x4_t p1 = *(const bf16x4_t*)(part + (size_t)s1 * TD + c);
  o.x += (float)p0[0] + (float)p1[0];
  o.y += (float)p0[1] + (float)p1[1];
  o.z += (float)p0[2] + (float)p1[2];
  o.w += (float)p0[3] + (float)p1[3];
  *(float4*)(outp + (size_t)t * TD + c) = o;
}

// ---------------- host launcher ----------------
extern "C" void kernel_launch(void* const* d_in, const int* in_sizes, int n_in,
                              void* d_out, int out_size, void* d_ws, size_t ws_size,
                              hipStream_t stream) {
  (void)in_sizes; (void)n_in; (void)out_size;
  const float* hidden = (const float*)d_in[0];
  const int*   mask   = (const int*)d_in[1];
  const float* ln1_g  = (const float*)d_in[2];
  const float* ln1_b  = (const float*)d_in[3];
  const float* wq = (const float*)d_in[4];  const float* bq = (const float*)d_in[5];
  const float* wk = (const float*)d_in[6];  const float* bk = (const float*)d_in[7];
  const float* wv = (const float*)d_in[8];  const float* bv = (const float*)d_in[9];
  const float* wo = (const float*)d_in[10]; const float* bo = (const float*)d_in[11];
  const float* gate_w = (const float*)d_in[12];
  const float* gate_b = (const float*)d_in[13];
  const float* w1 = (const float*)d_in[14];
  const float* b1 = (const float*)d_in[15];
  const float* w2 = (const float*)d_in[16];
  const float* b2 = (const float*)d_in[17];
  const float* ln2_g = (const float*)d_in[18];
  const float* ln2_b = (const float*)d_in[19];

  float* outp  = (float*)d_out;
  float* gates = (float*)d_out + (size_t)TT * TD;

  char* ws = (char*)d_ws;
  __bf16* Apl  = (__bf16*)(ws + O_APL);
  __bf16* vT0p = (__bf16*)(ws + O_VT0);
  __bf16* vT1p = (__bf16*)(ws + O_VT1);
  __bf16* ctxh = (__bf16*)(ws + O_CTXH);
  __bf16* ctxm = (__bf16*)(ws + O_CTXM);
  __bf16* qkh  = (__bf16*)(ws + O_QKH);
  __bf16* qkm  = (__bf16*)(ws + O_QKM);
  float*  vcol = (float*)(ws + O_VCOL);
  __bf16* BTp  = (__bf16*)(ws + O_BT);
  __bf16* x2   = (__bf16*)(ws + O_X2);
  __bf16* xg   = (__bf16*)(ws + O_XG);   // also part[] (gemm2 output, after gemm1 consumed xg)
  __bf16* w1T  = (__bf16*)(ws + O_W1T);
  __bf16* w2T  = (__bf16*)(ws + O_W2T);
  char*   meta = ws + O_META;
  int*   cnt      = (int*)(meta + M_CNT);
  int*   fill     = (int*)(meta + M_FILL);
  int*   nrb_p    = (int*)(meta + M_NRB);
  int*   rb2e     = (int*)(meta + M_RB2E);
  int*   tok_e    = (int*)(meta + M_TOKE);
  float* tok_w    = (float*)(meta + M_TOKW);
  float* row_gw   = (float*)(meta + M_RGW);
  int*   tok_slot = (int*)(meta + M_TSLOT);
  __bf16* midg = (__bf16*)(ws + O_MIDG);

  long long midcap = (long long)ws_size - (long long)O_MIDG;
  int crb = (int)(midcap / (128LL * TH * 2));
  if (crb < 1) crb = 1;
  if (crb > NRB_MAX) crb = NRB_MAX;

  const size_t SA = (size_t)TT * TD;

  init_meta_k<<<1, 64, 0, stream>>>(cnt);
  ln1_split_k<<<TT, 256, 0, stream>>>(hidden, ln1_g, ln1_b, Apl);
  tpose_split2_k<<<dim3(24, 24, 3), dim3(32, 8), 0, stream>>>(
      wq, wk, wv, BTp, (size_t)2304 * TD, 1);
  gemm_split4_k<0><<<dim3(18, 64), 256, 0, stream>>>(
      Apl, Apl + SA, BTp, (size_t)2304 * TD,
      bq, bk, bv, nullptr, nullptr, qkh, qkm, vcol);
  vT_split2_k<<<dim3(16, 2, 192), dim3(32, 8), 0, stream>>>(vcol, vT0p, vT1p);
  attn_mfma_k<<<dim3(8, TNH, TB), 256, 0, stream>>>(
      qkh, qkm, vT0p, vT1p, mask, ctxh, ctxm);
  tpose_split2_k<<<dim3(24, 24, 1), dim3(32, 8), 0, stream>>>(
      wo, wo, wo, BTp, (size_t)TD * TD, 0);
  gemm_split4_k<1><<<dim3(6, 64), 256, 0, stream>>>(
      ctxh, ctxm, BTp, (size_t)TD * TD,
      bo, nullptr, nullptr, hidden, outp, nullptr, nullptr, nullptr);
  ln2_gate_k<<<TT, 256, 0, stream>>>(outp, ln2_g, ln2_b, gate_w, gate_b, x2, gates,
                                     tok_e, tok_w);
  hist_k<<<64, 256, 0, stream>>>(tok_e, cnt);
  prefix_k<<<1, 192, 0, stream>>>(cnt, fill, nrb_p, rb2e);
  slot_assign_k<<<64, 256, 0, stream>>>(tok_e, tok_w, fill, tok_slot, row_gw);
  copy_xg_k<<<TT, 192, 0, stream>>>(x2, tok_slot, xg);
  transpose_cast_k<<<dim3(TH / 32, TD / 32, TE), dim3(32, 8), 0, stream>>>(w1, w1T, TD, TH);
  transpose_cast_k<<<dim3(TD / 32, TH / 32, TE), dim3(32, 8), 0, stream>>>(w2, w2T, TH, TD);
  __bf16* part = xg;  // xg rows of chunk c are dead once gemm1(c) has read them
  for (int cb = 0; cb < NRB_MAX; cb += crb) {
    int nb = NRB_MAX - cb; if (nb > crb) nb = crb;
    gemm1_k<<<dim3(TH / 128, nb), 256, 0, stream>>>(xg, w1T, b1, rb2e, nrb_p, cb, midg);
    gemm2_k<<<dim3(TD / 128, nb), 256, 0, stream>>>(midg, w2T, b2, rb2e, nrb_p,
                                                    row_gw, cb, part);
  }
  gather_k<<<TT, 192, 0, stream>>>(part, tok_slot, outp);
}